// Round 3
// baseline (937.283 us; speedup 1.0000x reference)
//
#include <hip/hip_runtime.h>
#include <hip/hip_bf16.h>
#include <cstdint>
#include <cstddef>

#define N_NODES 50000
#define N_EDGES 800000
#define D_IN 128
#define D_H 512
#define D_OUT 256
#define N_GRAPHS 512

#define BM 128
#define BN 128
#define BK 32

// fixed-point scale for deterministic integer aggregation
#define AGG_SCALE 65536.0f
#define AGG_INV (1.0f / 65536.0f)

typedef __bf16 v8bf __attribute__((ext_vector_type(8)));
typedef float v4f __attribute__((ext_vector_type(4)));

__device__ __forceinline__ float bf2f(unsigned short b) {
  return __uint_as_float(((unsigned int)b) << 16);
}
__device__ __forceinline__ unsigned short f2bf(float f) {
  unsigned int u = __float_as_uint(f);
  u += 0x7FFFu + ((u >> 16) & 1u);   // RNE
  return (unsigned short)(u >> 16);
}

__device__ __forceinline__ void gload_lds16(const void* g, void* l) {
  __builtin_amdgcn_global_load_lds(
      (const __attribute__((address_space(1))) void*)g,
      (__attribute__((address_space(3))) void*)l, 16, 0, 0);
}

// ---------------- dtype detector -------------------------------------------
// flags[0]=1 if float arrays are f32 (else bf16)
// flags[1]=1 if edge_index is int64 (else int32)
// flags[2]=1 if batch is int64 (else int32)
__global__ void k_detect(const void* __restrict__ x,
                         const void* __restrict__ ei,
                         const void* __restrict__ batch,
                         int* __restrict__ flags) {
  __shared__ int cnt[3];
  int t = threadIdx.x;
  if (t < 3) cnt[t] = 0;
  __syncthreads();
  const unsigned short* xs = (const unsigned short*)x;
  int c0 = 0;
  for (int i = t; i < 4096; i += 256) {
    unsigned int e = (xs[i] >> 7) & 0xFFu;
    if (e >= 0x90u) c0++;   // |v| >= 2^17 as bf16: impossible for N(0,1)
  }
  atomicAdd(&cnt[0], c0);
  const int* e32 = (const int*)ei;
  int c1 = 0;
  for (int i = t; i < 512; i += 256)
    if (e32[2 * i + 1] != 0) c1++;   // int64 -> high words all zero
  atomicAdd(&cnt[1], c1);
  const int* b32 = (const int*)batch;
  int c2 = 0;
  {
    int w = (N_NODES - 512) + 2 * t + 1;   // odd word near tail, < N_NODES
    if (b32[w] != 0) c2++;
  }
  atomicAdd(&cnt[2], c2);
  __syncthreads();
  if (t == 0) {
    flags[0] = (cnt[0] > 16) ? 1 : 0;
    flags[1] = (cnt[1] == 0) ? 1 : 0;
    flags[2] = (cnt[2] == 0) ? 1 : 0;
  }
}

// ---------------- weight transpose (B^T layout for GEMM staging) ------------
__global__ void k_transpose(const void* __restrict__ src,
                            unsigned short* __restrict__ dst,
                            const int* __restrict__ flags, int R, int C) {
  int i = blockIdx.x * 256 + threadIdx.x;
  if (i < R * C) {
    int r = i / C, c = i - r * C;
    unsigned short v = flags[0] ? f2bf(((const float*)src)[i])
                                : ((const unsigned short*)src)[i];
    dst[c * R + r] = v;
  }
}

// ---------------- aggregation (deterministic int32 fixed-point) -------------
__global__ void k_init(const void* __restrict__ x, int* __restrict__ agg,
                       const int* __restrict__ flags, int n) {
  int i = blockIdx.x * 256 + threadIdx.x;
  if (i < n) {
    float v = flags[0] ? ((const float*)x)[i]
                       : bf2f(((const unsigned short*)x)[i]);
    agg[i] = __float2int_rn(v * AGG_SCALE);   // (1+eps)*x with eps=0
  }
}

__global__ __launch_bounds__(256) void k_scatter(
    const void* __restrict__ x, const int* __restrict__ ei,
    int* __restrict__ agg, const int* __restrict__ flags, int ne) {
  int e = blockIdx.x * 4 + (threadIdx.x >> 6);
  if (e >= ne) return;
  int lane = threadIdx.x & 63;
  bool fe64 = flags[1] != 0;
  int s = fe64 ? ei[2 * (size_t)e] : ei[e];
  int d = fe64 ? ei[2 * ((size_t)ne + e)] : ei[(size_t)ne + e];
  float f0, f1;
  if (flags[0]) {
    const float* xf = (const float*)x + (size_t)s * D_IN + lane * 2;
    f0 = xf[0];
    f1 = xf[1];
  } else {
    unsigned int px =
        ((const unsigned int*)x)[(size_t)s * (D_IN / 2) + lane];
    f0 = __uint_as_float((px & 0xFFFFu) << 16);
    f1 = __uint_as_float(px & 0xFFFF0000u);
  }
  // integer adds are associative -> bitwise-deterministic across launches
  atomicAdd(&agg[(size_t)d * D_IN + lane * 2], __float2int_rn(f0 * AGG_SCALE));
  atomicAdd(&agg[(size_t)d * D_IN + lane * 2 + 1], __float2int_rn(f1 * AGG_SCALE));
}

__global__ void k_cvt(const int* __restrict__ agg,
                      unsigned short* __restrict__ h0, int n) {
  int i = blockIdx.x * 256 + threadIdx.x;
  if (i < n) h0[i] = f2bf((float)agg[i] * AGG_INV);
}

// ---------------- MFMA GEMM: C = act(A @ W + bias) -------------------------
// A: [M x K] bf16 row-major; BT: [Nc x K] bf16 row-major (pre-transposed W)
// ACT: 0 = LeakyReLU(1.5), 1 = ReLU, 2 = none. OUTF32: write f32 else bf16.
template <int ACT, bool OUTF32>
__global__ __launch_bounds__(256, 2) void gemm_bt(
    const unsigned short* __restrict__ A,
    const unsigned short* __restrict__ BT,
    const void* __restrict__ bias, const int* __restrict__ flags,
    void* __restrict__ Cout, int M, int K, int Nc) {
  __shared__ __align__(16) unsigned short As[BM * BK];
  __shared__ __align__(16) unsigned short Bs[BN * BK];

  const int tid  = threadIdx.x;
  const int wave = tid >> 6;
  const int lane = tid & 63;
  const int quad = lane >> 4;
  const int l15  = lane & 15;
  const int m0 = blockIdx.x * BM;
  const int n0 = blockIdx.y * BN;
  const int wm = (wave >> 1) * 64;
  const int wn = (wave & 1) * 64;
  const bool fm = flags[0] != 0;

  v4f acc[4][4];
#pragma unroll
  for (int i = 0; i < 4; ++i)
#pragma unroll
    for (int j = 0; j < 4; ++j) acc[i][j] = (v4f){0.f, 0.f, 0.f, 0.f};

  const int nK = K / BK;
  for (int kt = 0; kt < nK; ++kt) {
    const int k0 = kt * BK;
    __syncthreads();  // previous-iter LDS reads done
    // Stage A/B tiles: 512 16B chunks each. LDS chunk L=(row=L>>2, slot=L&3)
    // holds global chunk (slot ^ (row&3)) -> XOR-swizzled fragment reads.
#pragma unroll
    for (int it = 0; it < 2; ++it) {
      int L = tid + it * 256;
      int row = L >> 2;
      int c = (L & 3) ^ (row & 3);
      int gr = m0 + row;
      gr = gr < M ? gr : (M - 1);
      gload_lds16(A + (size_t)gr * K + (k0 + c * 8),
                  As + (it * 256 + wave * 64) * 8);
      int gn = n0 + row;  // Nc is a multiple of 128 -> always valid
      gload_lds16(BT + (size_t)gn * K + (k0 + c * 8),
                  Bs + (it * 256 + wave * 64) * 8);
    }
    __syncthreads();  // staging drained (vmcnt(0) before barrier)

    v8bf af[4], bfr[4];
#pragma unroll
    for (int mi = 0; mi < 4; ++mi) {
      int r = wm + mi * 16 + l15;
      int cc = quad ^ (r & 3);
      af[mi] = *(const v8bf*)(As + (r * 4 + cc) * 8);
    }
#pragma unroll
    for (int ni = 0; ni < 4; ++ni) {
      int r = wn + ni * 16 + l15;
      int cc = quad ^ (r & 3);
      bfr[ni] = *(const v8bf*)(Bs + (r * 4 + cc) * 8);
    }
#pragma unroll
    for (int mi = 0; mi < 4; ++mi)
#pragma unroll
      for (int ni = 0; ni < 4; ++ni)
        acc[mi][ni] = __builtin_amdgcn_mfma_f32_16x16x32_bf16(
            af[mi], bfr[ni], acc[mi][ni], 0, 0, 0);
  }

  // Epilogue: C/D layout col = lane&15, row = quad*4 + reg
#pragma unroll
  for (int ni = 0; ni < 4; ++ni) {
    int col = n0 + wn + ni * 16 + l15;
    float bv = fm ? ((const float*)bias)[col]
                  : bf2f(((const unsigned short*)bias)[col]);
#pragma unroll
    for (int mi = 0; mi < 4; ++mi) {
#pragma unroll
      for (int rg = 0; rg < 4; ++rg) {
        int row = m0 + wm + mi * 16 + quad * 4 + rg;
        if (row < M) {
          float v = acc[mi][ni][rg] + bv;
          if (ACT == 0) v = v > 0.f ? v : 1.5f * v;
          if (ACT == 1) v = v > 0.f ? v : 0.f;
          if (OUTF32)
            ((float*)Cout)[(size_t)row * Nc + col] = v;
          else
            ((unsigned short*)Cout)[(size_t)row * Nc + col] = f2bf(v);
        }
      }
    }
  }
}

// ---------------- mean pool over sorted batch ------------------------------
__global__ __launch_bounds__(256) void k_pool(
    const unsigned short* __restrict__ h, const int* __restrict__ batch,
    const int* __restrict__ flags, unsigned short* __restrict__ pooled) {
  __shared__ int bounds[2];
  int g = blockIdx.x;
  int t = threadIdx.x;
  bool b64 = flags[2] != 0;
  if (t < 2) {
    int key = g + t;
    int lo = 0, hi = N_NODES;
    while (lo < hi) {
      int mid = (lo + hi) >> 1;
      int bv = b64 ? batch[2 * (size_t)mid] : batch[mid];
      if (bv < key) lo = mid + 1; else hi = mid;
    }
    bounds[t] = lo;
  }
  __syncthreads();
  int s0 = bounds[0], s1 = bounds[1];
  float a0 = 0.f, a1 = 0.f;
  for (int r = s0; r < s1; ++r) {
    a0 += bf2f(h[(size_t)r * D_H + t]);
    a1 += bf2f(h[(size_t)r * D_H + t + 256]);
  }
  float inv = 1.0f / fmaxf((float)(s1 - s0), 1.0f);
  pooled[(size_t)g * D_H + t] = f2bf(a0 * inv);
  pooled[(size_t)g * D_H + t + 256] = f2bf(a1 * inv);
}

// ---------------- row L2-normalize -----------------------------------------
__global__ __launch_bounds__(256) void k_norm(const float* __restrict__ of,
                                              const int* __restrict__ flags,
                                              void* __restrict__ out) {
  __shared__ float red[4];
  int g = blockIdx.x, t = threadIdx.x;
  float v = of[g * D_OUT + t];
  float s = v * v;
#pragma unroll
  for (int o = 32; o > 0; o >>= 1) s += __shfl_xor(s, o, 64);
  if ((t & 63) == 0) red[t >> 6] = s;
  __syncthreads();
  float tot = red[0] + red[1] + red[2] + red[3];
  float inv = 1.0f / fmaxf(sqrtf(tot), 1e-12f);
  float r = v * inv;
  if (flags[0])
    ((float*)out)[g * D_OUT + t] = r;
  else
    ((unsigned short*)out)[g * D_OUT + t] = f2bf(r);
}

// ---------------- launcher --------------------------------------------------
extern "C" void kernel_launch(void* const* d_in, const int* in_sizes, int n_in,
                              void* d_out, int out_size, void* d_ws,
                              size_t ws_size, hipStream_t stream) {
  const void* x    = d_in[0];
  const int* ei    = (const int*)d_in[1];
  const int* batch = (const int*)d_in[2];
  const void* W1 = d_in[3];
  const void* b1 = d_in[4];
  const void* W2 = d_in[5];
  const void* b2 = d_in[6];
  const void* W3 = d_in[7];
  const void* b3 = d_in[8];
  const void* W4 = d_in[9];
  const void* b4 = d_in[10];
  const void* Wl = d_in[11];
  const void* bl = d_in[12];

  char* ws = (char*)d_ws;
  size_t off = 0;
  auto alloc = [&](size_t bytes) {
    void* p = ws + off;
    off += (bytes + 255) & ~(size_t)255;
    return p;
  };
  // small buffers first
  int* flags           = (int*)alloc(64);
  unsigned short* W1T  = (unsigned short*)alloc((size_t)D_IN * D_H * 2);
  unsigned short* W2T  = (unsigned short*)alloc((size_t)D_H * D_H * 2);
  unsigned short* W3T  = (unsigned short*)alloc((size_t)D_H * D_H * 2);
  unsigned short* W4T  = (unsigned short*)alloc((size_t)D_H * D_H * 2);
  unsigned short* WlT  = (unsigned short*)alloc((size_t)D_H * D_OUT * 2);
  unsigned short* pooled = (unsigned short*)alloc((size_t)N_GRAPHS * D_H * 2);
  float* outf          = (float*)alloc((size_t)N_GRAPHS * D_OUT * 4);
  // two big slots (51.2 MB each), aliased to cut footprint to ~106 MB:
  //   S1: agg(int32, 25.6MB) -> dead -> hA(bf16, 51.2MB)
  //   S2: h0(bf16, 12.8MB)   -> dead -> hB(bf16, 51.2MB)
  void* S1 = alloc((size_t)N_NODES * D_H * 2);
  void* S2 = alloc((size_t)N_NODES * D_H * 2);
  int* agg           = (int*)S1;
  unsigned short* hA = (unsigned short*)S1;
  unsigned short* h0 = (unsigned short*)S2;
  unsigned short* hB = (unsigned short*)S2;

  k_detect<<<1, 256, 0, stream>>>(x, ei, batch, flags);

  // weights -> B^T layout (re-done every launch; ws is re-poisoned)
  k_transpose<<<(D_IN * D_H + 255) / 256, 256, 0, stream>>>(W1, W1T, flags, D_IN, D_H);
  k_transpose<<<(D_H * D_H + 255) / 256, 256, 0, stream>>>(W2, W2T, flags, D_H, D_H);
  k_transpose<<<(D_H * D_H + 255) / 256, 256, 0, stream>>>(W3, W3T, flags, D_H, D_H);
  k_transpose<<<(D_H * D_H + 255) / 256, 256, 0, stream>>>(W4, W4T, flags, D_H, D_H);
  k_transpose<<<(D_H * D_OUT + 255) / 256, 256, 0, stream>>>(Wl, WlT, flags, D_H, D_OUT);

  // GIN aggregation: agg = x + segment_sum(x[src] -> dst), int32 fixed-point
  k_init<<<(N_NODES * D_IN + 255) / 256, 256, 0, stream>>>(x, agg, flags, N_NODES * D_IN);
  k_scatter<<<(N_EDGES + 3) / 4, 256, 0, stream>>>(x, ei, agg, flags, N_EDGES);
  k_cvt<<<(N_NODES * D_IN + 255) / 256, 256, 0, stream>>>(agg, h0, N_NODES * D_IN);

  dim3 gN((N_NODES + BM - 1) / BM, D_H / BN);
  gemm_bt<0, false><<<gN, 256, 0, stream>>>(h0, W1T, b1, flags, hA, N_NODES, D_IN, D_H);
  gemm_bt<1, false><<<gN, 256, 0, stream>>>(hA, W2T, b2, flags, hB, N_NODES, D_H, D_H);
  gemm_bt<1, false><<<gN, 256, 0, stream>>>(hB, W3T, b3, flags, hA, N_NODES, D_H, D_H);
  gemm_bt<2, false><<<gN, 256, 0, stream>>>(hA, W4T, b4, flags, hB, N_NODES, D_H, D_H);

  k_pool<<<N_GRAPHS, 256, 0, stream>>>(hB, batch, flags, pooled);

  dim3 g5(N_GRAPHS / BM, D_OUT / BN);
  gemm_bt<2, true><<<g5, 256, 0, stream>>>(pooled, WlT, bl, flags, outf, N_GRAPHS, D_H, D_OUT);

  k_norm<<<N_GRAPHS, 256, 0, stream>>>(outf, flags, (unsigned short*)d_out);
}

// Round 4
// 670.132 us; speedup vs baseline: 1.3987x; 1.3987x over previous
//
#include <hip/hip_runtime.h>
#include <hip/hip_bf16.h>
#include <cstdint>
#include <cstddef>

#define N_NODES 50000
#define N_EDGES 800000
#define D_IN 128
#define D_H 512
#define D_OUT 256
#define N_GRAPHS 512

#define BM 128
#define BN 128
#define BK 32

// fixed-point scale for deterministic integer aggregation
#define AGG_SCALE 65536.0f
#define AGG_INV (1.0f / 65536.0f)

typedef __bf16 v8bf __attribute__((ext_vector_type(8)));
typedef float v4f __attribute__((ext_vector_type(4)));

__device__ __forceinline__ float bf2f(unsigned short b) {
  return __uint_as_float(((unsigned int)b) << 16);
}
__device__ __forceinline__ unsigned short f2bf(float f) {
  unsigned int u = __float_as_uint(f);
  u += 0x7FFFu + ((u >> 16) & 1u);   // RNE
  return (unsigned short)(u >> 16);
}

__device__ __forceinline__ void gload_lds16(const void* g, void* l) {
  __builtin_amdgcn_global_load_lds(
      (const __attribute__((address_space(1))) void*)g,
      (__attribute__((address_space(3))) void*)l, 16, 0, 0);
}

// ---------------- dtype detector -------------------------------------------
// flags[0]=1 if float arrays are f32 (else bf16)
// flags[1]=1 if edge_index is int64 (else int32)
// flags[2]=1 if batch is int64 (else int32)
__global__ void k_detect(const void* __restrict__ x,
                         const void* __restrict__ ei,
                         const void* __restrict__ batch,
                         int* __restrict__ flags) {
  __shared__ int cnt[3];
  int t = threadIdx.x;
  if (t < 3) cnt[t] = 0;
  __syncthreads();
  const unsigned short* xs = (const unsigned short*)x;
  int c0 = 0;
  for (int i = t; i < 4096; i += 256) {
    unsigned int e = (xs[i] >> 7) & 0xFFu;
    if (e >= 0x90u) c0++;   // |v| >= 2^17 as bf16: impossible for N(0,1)
  }
  atomicAdd(&cnt[0], c0);
  const int* e32 = (const int*)ei;
  int c1 = 0;
  for (int i = t; i < 512; i += 256)
    if (e32[2 * i + 1] != 0) c1++;   // int64 -> high words all zero
  atomicAdd(&cnt[1], c1);
  const int* b32 = (const int*)batch;
  int c2 = 0;
  {
    int w = (N_NODES - 512) + 2 * t + 1;   // odd word near tail, < N_NODES
    if (b32[w] != 0) c2++;
  }
  atomicAdd(&cnt[2], c2);
  __syncthreads();
  if (t == 0) {
    flags[0] = (cnt[0] > 16) ? 1 : 0;
    flags[1] = (cnt[1] == 0) ? 1 : 0;
    flags[2] = (cnt[2] == 0) ? 1 : 0;
  }
}

// ---------------- weight transpose (B^T layout for GEMM staging) ------------
__global__ void k_transpose(const void* __restrict__ src,
                            unsigned short* __restrict__ dst,
                            const int* __restrict__ flags, int R, int C) {
  int i = blockIdx.x * 256 + threadIdx.x;
  if (i < R * C) {
    int r = i / C, c = i - r * C;
    unsigned short v = flags[0] ? f2bf(((const float*)src)[i])
                                : ((const unsigned short*)src)[i];
    dst[c * R + r] = v;
  }
}

// ---------------- CSR build -------------------------------------------------
__global__ void k_zero(int* __restrict__ p, int n) {
  int i = blockIdx.x * 256 + threadIdx.x;
  if (i < n) p[i] = 0;
}

__global__ void k_count(const int* __restrict__ ei, int* __restrict__ deg,
                        const int* __restrict__ flags, int ne) {
  int e = blockIdx.x * 256 + threadIdx.x;
  if (e >= ne) return;
  int d = flags[1] ? ei[2 * ((size_t)ne + e)] : ei[(size_t)ne + e];
  atomicAdd(&deg[d], 1);
}

// single block, 1024 threads: exclusive scan of deg -> rowptr, cur
__global__ __launch_bounds__(1024) void k_scan(const int* __restrict__ deg,
                                               int* __restrict__ rowptr,
                                               int* __restrict__ cur) {
  __shared__ int part[1024];
  const int t = threadIdx.x;
  const int CH = (N_NODES + 1023) / 1024;   // 49
  const int base = t * CH;
  int own = 0;
  for (int i = 0; i < CH; ++i) {
    int idx = base + i;
    if (idx < N_NODES) own += deg[idx];
  }
  part[t] = own;
  __syncthreads();
  // Hillis-Steele inclusive scan
  for (int offd = 1; offd < 1024; offd <<= 1) {
    int v = part[t];
    int add = (t >= offd) ? part[t - offd] : 0;
    __syncthreads();
    part[t] = v + add;
    __syncthreads();
  }
  int run = part[t] - own;   // exclusive base for this chunk
  for (int i = 0; i < CH; ++i) {
    int idx = base + i;
    if (idx < N_NODES) {
      rowptr[idx] = run;
      cur[idx] = run;
      run += deg[idx];
    }
  }
  if (t == 1023) rowptr[N_NODES] = part[1023];
}

__global__ void k_fill(const int* __restrict__ ei, int* __restrict__ cur,
                       int* __restrict__ elist, const int* __restrict__ flags,
                       int ne) {
  int e = blockIdx.x * 256 + threadIdx.x;
  if (e >= ne) return;
  bool fe64 = flags[1] != 0;
  int s = fe64 ? ei[2 * (size_t)e] : ei[e];
  int d = fe64 ? ei[2 * ((size_t)ne + e)] : ei[(size_t)ne + e];
  int pos = atomicAdd(&cur[d], 1);
  elist[pos] = s;
}

// ---------------- gather aggregation (one wave per node) --------------------
// h0[node] = bf16( x[node] + sum_{s in in(node)} x[s] )  via int32 fixed-point
// (integer adds associative -> bitwise-deterministic regardless of elist order)
__global__ __launch_bounds__(256) void k_gather(
    const void* __restrict__ x, const int* __restrict__ rowptr,
    const int* __restrict__ elist, const int* __restrict__ flags,
    unsigned short* __restrict__ h0) {
  int node = blockIdx.x * 4 + (threadIdx.x >> 6);
  if (node >= N_NODES) return;
  int lane = threadIdx.x & 63;
  int s0 = rowptr[node], s1 = rowptr[node + 1];
  int a0, a1;
  if (flags[0]) {
    const float* xf = (const float*)x;
    const float* xr = xf + (size_t)node * D_IN + lane * 2;
    a0 = __float2int_rn(xr[0] * AGG_SCALE);
    a1 = __float2int_rn(xr[1] * AGG_SCALE);
    for (int j = s0; j < s1; ++j) {
      int s = elist[j];
      const float* xs = xf + (size_t)s * D_IN + lane * 2;
      a0 += __float2int_rn(xs[0] * AGG_SCALE);
      a1 += __float2int_rn(xs[1] * AGG_SCALE);
    }
  } else {
    const unsigned int* xu = (const unsigned int*)x;
    unsigned int px = xu[(size_t)node * (D_IN / 2) + lane];
    a0 = __float2int_rn(__uint_as_float((px & 0xFFFFu) << 16) * AGG_SCALE);
    a1 = __float2int_rn(__uint_as_float(px & 0xFFFF0000u) * AGG_SCALE);
    for (int j = s0; j < s1; ++j) {
      int s = elist[j];
      unsigned int p = xu[(size_t)s * (D_IN / 2) + lane];
      a0 += __float2int_rn(__uint_as_float((p & 0xFFFFu) << 16) * AGG_SCALE);
      a1 += __float2int_rn(__uint_as_float(p & 0xFFFF0000u) * AGG_SCALE);
    }
  }
  h0[(size_t)node * D_IN + lane * 2] = f2bf((float)a0 * AGG_INV);
  h0[(size_t)node * D_IN + lane * 2 + 1] = f2bf((float)a1 * AGG_INV);
}

// ---------------- MFMA GEMM: C = act(A @ W + bias) -------------------------
// A: [M x K] bf16 row-major; BT: [Nc x K] bf16 row-major (pre-transposed W)
// ACT: 0 = LeakyReLU(1.5), 1 = ReLU, 2 = none. OUTF32: write f32 else bf16.
template <int ACT, bool OUTF32>
__global__ __launch_bounds__(256, 2) void gemm_bt(
    const unsigned short* __restrict__ A,
    const unsigned short* __restrict__ BT,
    const void* __restrict__ bias, const int* __restrict__ flags,
    void* __restrict__ Cout, int M, int K, int Nc) {
  __shared__ __align__(16) unsigned short As[BM * BK];
  __shared__ __align__(16) unsigned short Bs[BN * BK];

  const int tid  = threadIdx.x;
  const int wave = tid >> 6;
  const int lane = tid & 63;
  const int quad = lane >> 4;
  const int l15  = lane & 15;
  const int m0 = blockIdx.x * BM;
  const int n0 = blockIdx.y * BN;
  const int wm = (wave >> 1) * 64;
  const int wn = (wave & 1) * 64;
  const bool fm = flags[0] != 0;

  v4f acc[4][4];
#pragma unroll
  for (int i = 0; i < 4; ++i)
#pragma unroll
    for (int j = 0; j < 4; ++j) acc[i][j] = (v4f){0.f, 0.f, 0.f, 0.f};

  const int nK = K / BK;
  for (int kt = 0; kt < nK; ++kt) {
    const int k0 = kt * BK;
    __syncthreads();  // previous-iter LDS reads done
    // Stage A/B tiles: 512 16B chunks each. LDS chunk L=(row=L>>2, slot=L&3)
    // holds global chunk (slot ^ (row&3)) -> XOR-swizzled fragment reads.
#pragma unroll
    for (int it = 0; it < 2; ++it) {
      int L = tid + it * 256;
      int row = L >> 2;
      int c = (L & 3) ^ (row & 3);
      int gr = m0 + row;
      gr = gr < M ? gr : (M - 1);
      gload_lds16(A + (size_t)gr * K + (k0 + c * 8),
                  As + (it * 256 + wave * 64) * 8);
      int gn = n0 + row;  // Nc is a multiple of 128 -> always valid
      gload_lds16(BT + (size_t)gn * K + (k0 + c * 8),
                  Bs + (it * 256 + wave * 64) * 8);
    }
    __syncthreads();  // staging drained (vmcnt(0) before barrier)

    v8bf af[4], bfr[4];
#pragma unroll
    for (int mi = 0; mi < 4; ++mi) {
      int r = wm + mi * 16 + l15;
      int cc = quad ^ (r & 3);
      af[mi] = *(const v8bf*)(As + (r * 4 + cc) * 8);
    }
#pragma unroll
    for (int ni = 0; ni < 4; ++ni) {
      int r = wn + ni * 16 + l15;
      int cc = quad ^ (r & 3);
      bfr[ni] = *(const v8bf*)(Bs + (r * 4 + cc) * 8);
    }
#pragma unroll
    for (int mi = 0; mi < 4; ++mi)
#pragma unroll
      for (int ni = 0; ni < 4; ++ni)
        acc[mi][ni] = __builtin_amdgcn_mfma_f32_16x16x32_bf16(
            af[mi], bfr[ni], acc[mi][ni], 0, 0, 0);
  }

  // Epilogue: C/D layout col = lane&15, row = quad*4 + reg
#pragma unroll
  for (int ni = 0; ni < 4; ++ni) {
    int col = n0 + wn + ni * 16 + l15;
    float bv = fm ? ((const float*)bias)[col]
                  : bf2f(((const unsigned short*)bias)[col]);
#pragma unroll
    for (int mi = 0; mi < 4; ++mi) {
#pragma unroll
      for (int rg = 0; rg < 4; ++rg) {
        int row = m0 + wm + mi * 16 + quad * 4 + rg;
        if (row < M) {
          float v = acc[mi][ni][rg] + bv;
          if (ACT == 0) v = v > 0.f ? v : 1.5f * v;
          if (ACT == 1) v = v > 0.f ? v : 0.f;
          if (OUTF32)
            ((float*)Cout)[(size_t)row * Nc + col] = v;
          else
            ((unsigned short*)Cout)[(size_t)row * Nc + col] = f2bf(v);
        }
      }
    }
  }
}

// ---------------- mean pool over sorted batch ------------------------------
__global__ __launch_bounds__(256) void k_pool(
    const unsigned short* __restrict__ h, const int* __restrict__ batch,
    const int* __restrict__ flags, unsigned short* __restrict__ pooled) {
  __shared__ int bounds[2];
  int g = blockIdx.x;
  int t = threadIdx.x;
  bool b64 = flags[2] != 0;
  if (t < 2) {
    int key = g + t;
    int lo = 0, hi = N_NODES;
    while (lo < hi) {
      int mid = (lo + hi) >> 1;
      int bv = b64 ? batch[2 * (size_t)mid] : batch[mid];
      if (bv < key) lo = mid + 1; else hi = mid;
    }
    bounds[t] = lo;
  }
  __syncthreads();
  int s0 = bounds[0], s1 = bounds[1];
  float a0 = 0.f, a1 = 0.f;
  for (int r = s0; r < s1; ++r) {
    a0 += bf2f(h[(size_t)r * D_H + t]);
    a1 += bf2f(h[(size_t)r * D_H + t + 256]);
  }
  float inv = 1.0f / fmaxf((float)(s1 - s0), 1.0f);
  pooled[(size_t)g * D_H + t] = f2bf(a0 * inv);
  pooled[(size_t)g * D_H + t + 256] = f2bf(a1 * inv);
}

// ---------------- row L2-normalize -----------------------------------------
__global__ __launch_bounds__(256) void k_norm(const float* __restrict__ of,
                                              const int* __restrict__ flags,
                                              void* __restrict__ out) {
  __shared__ float red[4];
  int g = blockIdx.x, t = threadIdx.x;
  float v = of[g * D_OUT + t];
  float s = v * v;
#pragma unroll
  for (int o = 32; o > 0; o >>= 1) s += __shfl_xor(s, o, 64);
  if ((t & 63) == 0) red[t >> 6] = s;
  __syncthreads();
  float tot = red[0] + red[1] + red[2] + red[3];
  float inv = 1.0f / fmaxf(sqrtf(tot), 1e-12f);
  float r = v * inv;
  if (flags[0])
    ((float*)out)[g * D_OUT + t] = r;
  else
    ((unsigned short*)out)[g * D_OUT + t] = f2bf(r);
}

// ---------------- launcher --------------------------------------------------
extern "C" void kernel_launch(void* const* d_in, const int* in_sizes, int n_in,
                              void* d_out, int out_size, void* d_ws,
                              size_t ws_size, hipStream_t stream) {
  const void* x    = d_in[0];
  const int* ei    = (const int*)d_in[1];
  const int* batch = (const int*)d_in[2];
  const void* W1 = d_in[3];
  const void* b1 = d_in[4];
  const void* W2 = d_in[5];
  const void* b2 = d_in[6];
  const void* W3 = d_in[7];
  const void* b3 = d_in[8];
  const void* W4 = d_in[9];
  const void* b4 = d_in[10];
  const void* Wl = d_in[11];
  const void* bl = d_in[12];

  char* ws = (char*)d_ws;
  size_t off = 0;
  auto alloc = [&](size_t bytes) {
    void* p = ws + off;
    off += (bytes + 255) & ~(size_t)255;
    return p;
  };
  // small buffers first
  int* flags           = (int*)alloc(64);
  unsigned short* W1T  = (unsigned short*)alloc((size_t)D_IN * D_H * 2);
  unsigned short* W2T  = (unsigned short*)alloc((size_t)D_H * D_H * 2);
  unsigned short* W3T  = (unsigned short*)alloc((size_t)D_H * D_H * 2);
  unsigned short* W4T  = (unsigned short*)alloc((size_t)D_H * D_H * 2);
  unsigned short* WlT  = (unsigned short*)alloc((size_t)D_H * D_OUT * 2);
  unsigned short* pooled = (unsigned short*)alloc((size_t)N_GRAPHS * D_H * 2);
  float* outf          = (float*)alloc((size_t)N_GRAPHS * D_OUT * 4);
  // CSR buffers
  int* deg    = (int*)alloc((size_t)N_NODES * 4);
  int* rowptr = (int*)alloc(((size_t)N_NODES + 1) * 4);
  int* cur    = (int*)alloc((size_t)N_NODES * 4);
  int* elist  = (int*)alloc((size_t)N_EDGES * 4);
  // two big slots (51.2 MB each), aliased:
  //   S1: hA(bf16)            S2: h0(bf16, 12.8MB) -> dead -> hB(bf16)
  void* S1 = alloc((size_t)N_NODES * D_H * 2);
  void* S2 = alloc((size_t)N_NODES * D_H * 2);
  unsigned short* hA = (unsigned short*)S1;
  unsigned short* h0 = (unsigned short*)S2;
  unsigned short* hB = (unsigned short*)S2;

  k_detect<<<1, 256, 0, stream>>>(x, ei, batch, flags);

  // weights -> B^T layout (re-done every launch; ws is re-poisoned)
  k_transpose<<<(D_IN * D_H + 255) / 256, 256, 0, stream>>>(W1, W1T, flags, D_IN, D_H);
  k_transpose<<<(D_H * D_H + 255) / 256, 256, 0, stream>>>(W2, W2T, flags, D_H, D_H);
  k_transpose<<<(D_H * D_H + 255) / 256, 256, 0, stream>>>(W3, W3T, flags, D_H, D_H);
  k_transpose<<<(D_H * D_H + 255) / 256, 256, 0, stream>>>(W4, W4T, flags, D_H, D_H);
  k_transpose<<<(D_H * D_OUT + 255) / 256, 256, 0, stream>>>(Wl, WlT, flags, D_H, D_OUT);

  // CSR build + gather aggregation (replaces atomic scatter: kills 819MB of
  // atomic write-through HBM traffic seen in R3 profile)
  k_zero<<<(N_NODES + 255) / 256, 256, 0, stream>>>(deg, N_NODES);
  k_count<<<(N_EDGES + 255) / 256, 256, 0, stream>>>(ei, deg, flags, N_EDGES);
  k_scan<<<1, 1024, 0, stream>>>(deg, rowptr, cur);
  k_fill<<<(N_EDGES + 255) / 256, 256, 0, stream>>>(ei, cur, elist, flags, N_EDGES);
  k_gather<<<(N_NODES + 3) / 4, 256, 0, stream>>>(x, rowptr, elist, flags, h0);

  dim3 gN((N_NODES + BM - 1) / BM, D_H / BN);
  gemm_bt<0, false><<<gN, 256, 0, stream>>>(h0, W1T, b1, flags, hA, N_NODES, D_IN, D_H);
  gemm_bt<1, false><<<gN, 256, 0, stream>>>(hA, W2T, b2, flags, hB, N_NODES, D_H, D_H);
  gemm_bt<1, false><<<gN, 256, 0, stream>>>(hB, W3T, b3, flags, hA, N_NODES, D_H, D_H);
  gemm_bt<2, false><<<gN, 256, 0, stream>>>(hA, W4T, b4, flags, hB, N_NODES, D_H, D_H);

  k_pool<<<N_GRAPHS, 256, 0, stream>>>(hB, batch, flags, pooled);

  dim3 g5(N_GRAPHS / BM, D_OUT / BN);
  gemm_bt<2, true><<<g5, 256, 0, stream>>>(pooled, WlT, bl, flags, outf, N_GRAPHS, D_H, D_OUT);

  k_norm<<<N_GRAPHS, 256, 0, stream>>>(outf, flags, (unsigned short*)d_out);
}

// Round 5
// 539.423 us; speedup vs baseline: 1.7376x; 1.2423x over previous
//
#include <hip/hip_runtime.h>
#include <hip/hip_bf16.h>
#include <cstdint>
#include <cstddef>

#define N_NODES 50000
#define N_EDGES 800000
#define D_IN 128
#define D_H 512
#define D_OUT 256
#define N_GRAPHS 512

#define BM 128
#define BN 128
#define BK 64
#define NBLK ((N_NODES + 255) / 256)   // 196

// fixed-point scale for deterministic integer aggregation
#define AGG_SCALE 65536.0f
#define AGG_INV (1.0f / 65536.0f)

typedef __bf16 v8bf __attribute__((ext_vector_type(8)));
typedef float v4f __attribute__((ext_vector_type(4)));

__device__ __forceinline__ float bf2f(unsigned short b) {
  return __uint_as_float(((unsigned int)b) << 16);
}
__device__ __forceinline__ unsigned short f2bf(float f) {
  unsigned int u = __float_as_uint(f);
  u += 0x7FFFu + ((u >> 16) & 1u);   // RNE
  return (unsigned short)(u >> 16);
}

__device__ __forceinline__ void gload_lds16(const void* g, void* l) {
  __builtin_amdgcn_global_load_lds(
      (const __attribute__((address_space(1))) void*)g,
      (__attribute__((address_space(3))) void*)l, 16, 0, 0);
}

// ---------------- prep: zero deg + dtype detect (block 0) -------------------
// flags[0]=1 f32 floats; flags[1]=1 int64 edge_index; flags[2]=1 int64 batch
__global__ __launch_bounds__(256) void k_prep(const void* __restrict__ x,
                                              const void* __restrict__ ei,
                                              const void* __restrict__ batch,
                                              int* __restrict__ deg,
                                              int* __restrict__ flags) {
  int i = blockIdx.x * 256 + threadIdx.x;
  if (i < N_NODES) deg[i] = 0;
  if (blockIdx.x != 0) return;
  __shared__ int cnt[3];
  int t = threadIdx.x;
  if (t < 3) cnt[t] = 0;
  __syncthreads();
  const unsigned short* xs = (const unsigned short*)x;
  int c0 = 0;
  for (int k = t; k < 4096; k += 256) {
    unsigned int e = (xs[k] >> 7) & 0xFFu;
    if (e >= 0x90u) c0++;   // |v|>=2^17 as bf16: impossible for N(0,1)
  }
  atomicAdd(&cnt[0], c0);
  const int* e32 = (const int*)ei;
  int c1 = 0;
  for (int k = t; k < 512; k += 256)
    if (e32[2 * k + 1] != 0) c1++;   // int64 -> high words all zero
  atomicAdd(&cnt[1], c1);
  const int* b32 = (const int*)batch;
  int c2 = 0;
  {
    int w = (N_NODES - 512) + 2 * t + 1;   // odd word near tail, < N_NODES
    if (b32[w] != 0) c2++;
  }
  atomicAdd(&cnt[2], c2);
  __syncthreads();
  if (t == 0) {
    flags[0] = (cnt[0] > 16) ? 1 : 0;
    flags[1] = (cnt[1] == 0) ? 1 : 0;
    flags[2] = (cnt[2] == 0) ? 1 : 0;
  }
}

// ---------------- fused weight transposes (B^T layout) ----------------------
// segments: W1 128x512 | W2,W3,W4 512x512 | Wl 512x256
__global__ void k_transpose_all(const void* W1, const void* W2, const void* W3,
                                const void* W4, const void* Wl,
                                unsigned short* W1T, unsigned short* W2T,
                                unsigned short* W3T, unsigned short* W4T,
                                unsigned short* WlT,
                                const int* __restrict__ flags) {
  int i = blockIdx.x * 256 + threadIdx.x;
  const void* src;
  unsigned short* dst;
  int R, C, j;
  if (i < 65536)            { src = W1; dst = W1T; R = 128; C = 512; j = i; }
  else if (i < 327680)      { src = W2; dst = W2T; R = 512; C = 512; j = i - 65536; }
  else if (i < 589824)      { src = W3; dst = W3T; R = 512; C = 512; j = i - 327680; }
  else if (i < 851968)      { src = W4; dst = W4T; R = 512; C = 512; j = i - 589824; }
  else if (i < 983040)      { src = Wl; dst = WlT; R = 512; C = 256; j = i - 851968; }
  else return;
  int r = j / C, c = j - r * C;
  unsigned short v = flags[0] ? f2bf(((const float*)src)[j])
                              : ((const unsigned short*)src)[j];
  dst[c * R + r] = v;
}

// ---------------- CSR build -------------------------------------------------
__global__ void k_count(const int* __restrict__ ei, int* __restrict__ deg,
                        const int* __restrict__ flags, int ne) {
  int e = blockIdx.x * 256 + threadIdx.x;
  if (e >= ne) return;
  int d = flags[1] ? ei[2 * ((size_t)ne + e)] : ei[(size_t)ne + e];
  atomicAdd(&deg[d], 1);
}

// hierarchical exclusive scan: A) per-block local scan + partial sums
__global__ __launch_bounds__(256) void k_scanA(const int* __restrict__ deg,
                                               int* __restrict__ rowptr,
                                               int* __restrict__ part) {
  __shared__ int sh[256];
  int t = threadIdx.x;
  int i = blockIdx.x * 256 + t;
  int v = (i < N_NODES) ? deg[i] : 0;
  sh[t] = v;
  __syncthreads();
  for (int o = 1; o < 256; o <<= 1) {
    int a = sh[t];
    int b = (t >= o) ? sh[t - o] : 0;
    __syncthreads();
    sh[t] = a + b;
    __syncthreads();
  }
  if (i < N_NODES) rowptr[i] = sh[t] - v;   // local exclusive
  if (t == 255) part[blockIdx.x] = sh[255];
}

// B) single small block scans the 196 partials in-place (exclusive)
__global__ __launch_bounds__(256) void k_scanB(int* __restrict__ part,
                                               int* __restrict__ rowptr) {
  __shared__ int sh[256];
  int t = threadIdx.x;
  int v = (t < NBLK) ? part[t] : 0;
  sh[t] = v;
  __syncthreads();
  for (int o = 1; o < 256; o <<= 1) {
    int a = sh[t];
    int b = (t >= o) ? sh[t - o] : 0;
    __syncthreads();
    sh[t] = a + b;
    __syncthreads();
  }
  if (t < NBLK) part[t] = sh[t] - v;   // exclusive base per block
  if (t == 0) rowptr[N_NODES] = sh[255];
}

// C) add block base; init cur
__global__ __launch_bounds__(256) void k_scanC(int* __restrict__ rowptr,
                                               const int* __restrict__ part,
                                               int* __restrict__ cur) {
  int i = blockIdx.x * 256 + threadIdx.x;
  if (i < N_NODES) {
    int r = rowptr[i] + part[blockIdx.x];
    rowptr[i] = r;
    cur[i] = r;
  }
}

__global__ void k_fill(const int* __restrict__ ei, int* __restrict__ cur,
                       int* __restrict__ elist, const int* __restrict__ flags,
                       int ne) {
  int e = blockIdx.x * 256 + threadIdx.x;
  if (e >= ne) return;
  bool fe64 = flags[1] != 0;
  int s = fe64 ? ei[2 * (size_t)e] : ei[e];
  int d = fe64 ? ei[2 * ((size_t)ne + e)] : ei[(size_t)ne + e];
  int pos = atomicAdd(&cur[d], 1);
  elist[pos] = s;
}

// ---------------- gather aggregation (one wave per node) --------------------
// h0[node] = bf16( x[node] + sum_{s in in(node)} x[s] ) via int32 fixed-point
// (integer adds associative -> bitwise-deterministic regardless of elist order)
__global__ __launch_bounds__(256) void k_gather(
    const void* __restrict__ x, const int* __restrict__ rowptr,
    const int* __restrict__ elist, const int* __restrict__ flags,
    unsigned short* __restrict__ h0) {
  int node = blockIdx.x * 4 + (threadIdx.x >> 6);
  if (node >= N_NODES) return;
  int lane = threadIdx.x & 63;
  int s0 = rowptr[node], s1 = rowptr[node + 1];
  int a0, a1;
  if (flags[0]) {
    const float* xf = (const float*)x;
    const float* xr = xf + (size_t)node * D_IN + lane * 2;
    a0 = __float2int_rn(xr[0] * AGG_SCALE);
    a1 = __float2int_rn(xr[1] * AGG_SCALE);
    for (int j = s0; j < s1; ++j) {
      int s = elist[j];
      const float* xs = xf + (size_t)s * D_IN + lane * 2;
      a0 += __float2int_rn(xs[0] * AGG_SCALE);
      a1 += __float2int_rn(xs[1] * AGG_SCALE);
    }
  } else {
    const unsigned int* xu = (const unsigned int*)x;
    unsigned int px = xu[(size_t)node * (D_IN / 2) + lane];
    a0 = __float2int_rn(__uint_as_float((px & 0xFFFFu) << 16) * AGG_SCALE);
    a1 = __float2int_rn(__uint_as_float(px & 0xFFFF0000u) * AGG_SCALE);
    for (int j = s0; j < s1; ++j) {
      int s = elist[j];
      unsigned int p = xu[(size_t)s * (D_IN / 2) + lane];
      a0 += __float2int_rn(__uint_as_float((p & 0xFFFFu) << 16) * AGG_SCALE);
      a1 += __float2int_rn(__uint_as_float(p & 0xFFFF0000u) * AGG_SCALE);
    }
  }
  h0[(size_t)node * D_IN + lane * 2] = f2bf((float)a0 * AGG_INV);
  h0[(size_t)node * D_IN + lane * 2 + 1] = f2bf((float)a1 * AGG_INV);
}

// ---------------- MFMA GEMM: C = act(A @ W + bias), BK=64 ------------------
// A: [M x K] bf16 row-major; BT: [Nc x K] bf16 row-major (pre-transposed W)
// ACT: 0 = LeakyReLU(1.5), 1 = ReLU, 2 = none. OUTF32: write f32 else bf16.
template <int ACT, bool OUTF32>
__global__ __launch_bounds__(256, 2) void gemm_bt(
    const unsigned short* __restrict__ A,
    const unsigned short* __restrict__ BT,
    const void* __restrict__ bias, const int* __restrict__ flags,
    void* __restrict__ Cout, int M, int K, int Nc) {
  __shared__ __align__(16) unsigned short As[BM * BK];   // 16 KB
  __shared__ __align__(16) unsigned short Bs[BN * BK];   // 16 KB

  const int tid  = threadIdx.x;
  const int wave = tid >> 6;
  const int lane = tid & 63;
  const int quad = lane >> 4;
  const int l15  = lane & 15;
  const int m0 = blockIdx.x * BM;
  const int n0 = blockIdx.y * BN;
  const int wm = (wave >> 1) * 64;
  const int wn = (wave & 1) * 64;
  const bool fm = flags[0] != 0;

  v4f acc[4][4];
#pragma unroll
  for (int i = 0; i < 4; ++i)
#pragma unroll
    for (int j = 0; j < 4; ++j) acc[i][j] = (v4f){0.f, 0.f, 0.f, 0.f};

  const int nK = K / BK;   // 8 for K=512, 2 for K=128
  for (int kt = 0; kt < nK; ++kt) {
    const int k0 = kt * BK;
    __syncthreads();  // previous-iter LDS reads done
    // Stage A/B tiles: 1024 16B chunks each (row = L>>3, slot = L&7); slot
    // holds global chunk slot^(row&7) -> XOR-swizzled fragment reads. LDS
    // dest = base + lane*16 within each wave (global_load_lds constraint).
#pragma unroll
    for (int it = 0; it < 4; ++it) {
      int L = tid + it * 256;
      int row = L >> 3;
      int c = (L & 7) ^ (row & 7);
      int gr = m0 + row;
      gr = gr < M ? gr : (M - 1);
      gload_lds16(A + (size_t)gr * K + (k0 + c * 8), As + (size_t)L * 8);
      int gn = n0 + row;  // Nc multiple of 128 -> always valid
      gload_lds16(BT + (size_t)gn * K + (k0 + c * 8), Bs + (size_t)L * 8);
    }
    __syncthreads();  // staging drained

    // two k-half phases keep live fragment regs at 8 v8bf
#pragma unroll
    for (int h = 0; h < 2; ++h) {
      v8bf af[4], bfr[4];
#pragma unroll
      for (int mi = 0; mi < 4; ++mi) {
        int r = wm + mi * 16 + l15;
        int s = (h * 4 + quad) ^ (r & 7);
        af[mi] = *(const v8bf*)(As + (r * 8 + s) * 8);
      }
#pragma unroll
      for (int ni = 0; ni < 4; ++ni) {
        int r = wn + ni * 16 + l15;
        int s = (h * 4 + quad) ^ (r & 7);
        bfr[ni] = *(const v8bf*)(Bs + (r * 8 + s) * 8);
      }
#pragma unroll
      for (int mi = 0; mi < 4; ++mi)
#pragma unroll
        for (int ni = 0; ni < 4; ++ni)
          acc[mi][ni] = __builtin_amdgcn_mfma_f32_16x16x32_bf16(
              af[mi], bfr[ni], acc[mi][ni], 0, 0, 0);
    }
  }

  // Epilogue: C/D layout col = lane&15, row = quad*4 + reg
#pragma unroll
  for (int ni = 0; ni < 4; ++ni) {
    int col = n0 + wn + ni * 16 + l15;
    float bv = fm ? ((const float*)bias)[col]
                  : bf2f(((const unsigned short*)bias)[col]);
#pragma unroll
    for (int mi = 0; mi < 4; ++mi) {
#pragma unroll
      for (int rg = 0; rg < 4; ++rg) {
        int row = m0 + wm + mi * 16 + quad * 4 + rg;
        if (row < M) {
          float v = acc[mi][ni][rg] + bv;
          if (ACT == 0) v = v > 0.f ? v : 1.5f * v;
          if (ACT == 1) v = v > 0.f ? v : 0.f;
          if (OUTF32)
            ((float*)Cout)[(size_t)row * Nc + col] = v;
          else
            ((unsigned short*)Cout)[(size_t)row * Nc + col] = f2bf(v);
        }
      }
    }
  }
}

// ---------------- mean pool over sorted batch ------------------------------
__global__ __launch_bounds__(256) void k_pool(
    const unsigned short* __restrict__ h, const int* __restrict__ batch,
    const int* __restrict__ flags, unsigned short* __restrict__ pooled) {
  __shared__ int bounds[2];
  int g = blockIdx.x;
  int t = threadIdx.x;
  bool b64 = flags[2] != 0;
  if (t < 2) {
    int key = g + t;
    int lo = 0, hi = N_NODES;
    while (lo < hi) {
      int mid = (lo + hi) >> 1;
      int bv = b64 ? batch[2 * (size_t)mid] : batch[mid];
      if (bv < key) lo = mid + 1; else hi = mid;
    }
    bounds[t] = lo;
  }
  __syncthreads();
  int s0 = bounds[0], s1 = bounds[1];
  float a0 = 0.f, a1 = 0.f;
  for (int r = s0; r < s1; ++r) {
    a0 += bf2f(h[(size_t)r * D_H + t]);
    a1 += bf2f(h[(size_t)r * D_H + t + 256]);
  }
  float inv = 1.0f / fmaxf((float)(s1 - s0), 1.0f);
  pooled[(size_t)g * D_H + t] = f2bf(a0 * inv);
  pooled[(size_t)g * D_H + t + 256] = f2bf(a1 * inv);
}

// ---------------- row L2-normalize -----------------------------------------
__global__ __launch_bounds__(256) void k_norm(const float* __restrict__ of,
                                              const int* __restrict__ flags,
                                              void* __restrict__ out) {
  __shared__ float red[4];
  int g = blockIdx.x, t = threadIdx.x;
  float v = of[g * D_OUT + t];
  float s = v * v;
#pragma unroll
  for (int o = 32; o > 0; o >>= 1) s += __shfl_xor(s, o, 64);
  if ((t & 63) == 0) red[t >> 6] = s;
  __syncthreads();
  float tot = red[0] + red[1] + red[2] + red[3];
  float inv = 1.0f / fmaxf(sqrtf(tot), 1e-12f);
  float r = v * inv;
  if (flags[0])
    ((float*)out)[g * D_OUT + t] = r;
  else
    ((unsigned short*)out)[g * D_OUT + t] = f2bf(r);
}

// ---------------- launcher --------------------------------------------------
extern "C" void kernel_launch(void* const* d_in, const int* in_sizes, int n_in,
                              void* d_out, int out_size, void* d_ws,
                              size_t ws_size, hipStream_t stream) {
  const void* x    = d_in[0];
  const int* ei    = (const int*)d_in[1];
  const int* batch = (const int*)d_in[2];
  const void* W1 = d_in[3];
  const void* b1 = d_in[4];
  const void* W2 = d_in[5];
  const void* b2 = d_in[6];
  const void* W3 = d_in[7];
  const void* b3 = d_in[8];
  const void* W4 = d_in[9];
  const void* b4 = d_in[10];
  const void* Wl = d_in[11];
  const void* bl = d_in[12];

  char* ws = (char*)d_ws;
  size_t off = 0;
  auto alloc = [&](size_t bytes) {
    void* p = ws + off;
    off += (bytes + 255) & ~(size_t)255;
    return p;
  };
  // small buffers first
  int* flags           = (int*)alloc(64);
  unsigned short* W1T  = (unsigned short*)alloc((size_t)D_IN * D_H * 2);
  unsigned short* W2T  = (unsigned short*)alloc((size_t)D_H * D_H * 2);
  unsigned short* W3T  = (unsigned short*)alloc((size_t)D_H * D_H * 2);
  unsigned short* W4T  = (unsigned short*)alloc((size_t)D_H * D_H * 2);
  unsigned short* WlT  = (unsigned short*)alloc((size_t)D_H * D_OUT * 2);
  unsigned short* pooled = (unsigned short*)alloc((size_t)N_GRAPHS * D_H * 2);
  float* outf          = (float*)alloc((size_t)N_GRAPHS * D_OUT * 4);
  // CSR buffers
  int* deg    = (int*)alloc((size_t)N_NODES * 4);
  int* rowptr = (int*)alloc(((size_t)N_NODES + 1) * 4);
  int* cur    = (int*)alloc((size_t)N_NODES * 4);
  int* part   = (int*)alloc((size_t)NBLK * 4);
  int* elist  = (int*)alloc((size_t)N_EDGES * 4);
  // two big slots (51.2 MB each), aliased:
  //   S1: hA(bf16)            S2: h0(bf16, 12.8MB) -> dead -> hB(bf16)
  void* S1 = alloc((size_t)N_NODES * D_H * 2);
  void* S2 = alloc((size_t)N_NODES * D_H * 2);
  unsigned short* hA = (unsigned short*)S1;
  unsigned short* h0 = (unsigned short*)S2;
  unsigned short* hB = (unsigned short*)S2;

  // prep (zero deg + detect) runs first; everything branches on flags
  k_prep<<<NBLK, 256, 0, stream>>>(x, ei, batch, deg, flags);

  k_transpose_all<<<(983040 + 255) / 256, 256, 0, stream>>>(
      W1, W2, W3, W4, Wl, W1T, W2T, W3T, W4T, WlT, flags);

  // CSR build + gather aggregation
  k_count<<<(N_EDGES + 255) / 256, 256, 0, stream>>>(ei, deg, flags, N_EDGES);
  k_scanA<<<NBLK, 256, 0, stream>>>(deg, rowptr, part);
  k_scanB<<<1, 256, 0, stream>>>(part, rowptr);
  k_scanC<<<NBLK, 256, 0, stream>>>(rowptr, part, cur);
  k_fill<<<(N_EDGES + 255) / 256, 256, 0, stream>>>(ei, cur, elist, flags, N_EDGES);
  k_gather<<<(N_NODES + 3) / 4, 256, 0, stream>>>(x, rowptr, elist, flags, h0);

  dim3 gN((N_NODES + BM - 1) / BM, D_H / BN);
  gemm_bt<0, false><<<gN, 256, 0, stream>>>(h0, W1T, b1, flags, hA, N_NODES, D_IN, D_H);
  gemm_bt<1, false><<<gN, 256, 0, stream>>>(hA, W2T, b2, flags, hB, N_NODES, D_H, D_H);
  gemm_bt<1, false><<<gN, 256, 0, stream>>>(hB, W3T, b3, flags, hA, N_NODES, D_H, D_H);
  gemm_bt<2, false><<<gN, 256, 0, stream>>>(hA, W4T, b4, flags, hB, N_NODES, D_H, D_H);

  k_pool<<<N_GRAPHS, 256, 0, stream>>>(hB, batch, flags, pooled);

  dim3 g5(N_GRAPHS / BM, D_OUT / BN);
  gemm_bt<2, true><<<g5, 256, 0, stream>>>(pooled, WlT, bl, flags, outf, N_GRAPHS, D_H, D_OUT);

  k_norm<<<N_GRAPHS, 256, 0, stream>>>(outf, flags, (unsigned short*)d_out);
}

// Round 6
// 507.231 us; speedup vs baseline: 1.8478x; 1.0635x over previous
//
#include <hip/hip_runtime.h>
#include <hip/hip_bf16.h>
#include <cstdint>
#include <cstddef>

#define N_NODES 50000
#define N_EDGES 800000
#define D_IN 128
#define D_H 512
#define D_OUT 256
#define N_GRAPHS 512

#define BM 128
#define BN 128
#define BK 64
#define NBLK ((N_NODES + 255) / 256)   // 196
#define CT_SW 132                      // C-tile LDS stride in ushorts (264 B)

// fixed-point scale for deterministic integer aggregation
#define AGG_SCALE 65536.0f
#define AGG_INV (1.0f / 65536.0f)

typedef __bf16 v8bf __attribute__((ext_vector_type(8)));
typedef float v4f __attribute__((ext_vector_type(4)));
typedef int v4i __attribute__((ext_vector_type(4)));

__device__ __forceinline__ float bf2f(unsigned short b) {
  return __uint_as_float(((unsigned int)b) << 16);
}
__device__ __forceinline__ unsigned short f2bf(float f) {
  unsigned int u = __float_as_uint(f);
  u += 0x7FFFu + ((u >> 16) & 1u);   // RNE
  return (unsigned short)(u >> 16);
}

__device__ __forceinline__ void gload_lds16(const void* g, void* l) {
  __builtin_amdgcn_global_load_lds(
      (const __attribute__((address_space(1))) void*)g,
      (__attribute__((address_space(3))) void*)l, 16, 0, 0);
}

// ---------------- prep: zero deg + dtype detect (block 0) -------------------
// flags[0]=1 f32 floats; flags[1]=1 int64 edge_index; flags[2]=1 int64 batch
__global__ __launch_bounds__(256) void k_prep(const void* __restrict__ x,
                                              const void* __restrict__ ei,
                                              const void* __restrict__ batch,
                                              int* __restrict__ deg,
                                              int* __restrict__ flags) {
  int i = blockIdx.x * 256 + threadIdx.x;
  if (i < N_NODES) deg[i] = 0;
  if (blockIdx.x != 0) return;
  __shared__ int cnt[3];
  int t = threadIdx.x;
  if (t < 3) cnt[t] = 0;
  __syncthreads();
  const unsigned short* xs = (const unsigned short*)x;
  int c0 = 0;
  for (int k = t; k < 4096; k += 256) {
    unsigned int e = (xs[k] >> 7) & 0xFFu;
    if (e >= 0x90u) c0++;   // |v|>=2^17 as bf16: impossible for N(0,1)
  }
  atomicAdd(&cnt[0], c0);
  const int* e32 = (const int*)ei;
  int c1 = 0;
  for (int k = t; k < 512; k += 256)
    if (e32[2 * k + 1] != 0) c1++;   // int64 -> high words all zero
  atomicAdd(&cnt[1], c1);
  const int* b32 = (const int*)batch;
  int c2 = 0;
  {
    int w = (N_NODES - 512) + 2 * t + 1;   // odd word near tail, < N_NODES
    if (b32[w] != 0) c2++;
  }
  atomicAdd(&cnt[2], c2);
  __syncthreads();
  if (t == 0) {
    flags[0] = (cnt[0] > 16) ? 1 : 0;
    flags[1] = (cnt[1] == 0) ? 1 : 0;
    flags[2] = (cnt[2] == 0) ? 1 : 0;
  }
}

// ---------------- fused weight transposes (B^T layout) ----------------------
__global__ void k_transpose_all(const void* W1, const void* W2, const void* W3,
                                const void* W4, const void* Wl,
                                unsigned short* W1T, unsigned short* W2T,
                                unsigned short* W3T, unsigned short* W4T,
                                unsigned short* WlT,
                                const int* __restrict__ flags) {
  int i = blockIdx.x * 256 + threadIdx.x;
  const void* src;
  unsigned short* dst;
  int R, C, j;
  if (i < 65536)            { src = W1; dst = W1T; R = 128; C = 512; j = i; }
  else if (i < 327680)      { src = W2; dst = W2T; R = 512; C = 512; j = i - 65536; }
  else if (i < 589824)      { src = W3; dst = W3T; R = 512; C = 512; j = i - 327680; }
  else if (i < 851968)      { src = W4; dst = W4T; R = 512; C = 512; j = i - 589824; }
  else if (i < 983040)      { src = Wl; dst = WlT; R = 512; C = 256; j = i - 851968; }
  else return;
  int r = j / C, c = j - r * C;
  unsigned short v = flags[0] ? f2bf(((const float*)src)[j])
                              : ((const unsigned short*)src)[j];
  dst[c * R + r] = v;
}

// ---------------- x -> bf16 (halves gather traffic) -------------------------
__global__ __launch_bounds__(256) void k_cvtx(const void* __restrict__ x,
                                              const int* __restrict__ flags,
                                              unsigned int* __restrict__ xbf) {
  int i = blockIdx.x * 256 + threadIdx.x;   // dword index (2 bf16)
  if (i >= N_NODES * D_IN / 2) return;
  if (flags[0]) {
    const float* xf = (const float*)x + (size_t)i * 2;
    xbf[i] = (unsigned int)f2bf(xf[0]) | ((unsigned int)f2bf(xf[1]) << 16);
  } else {
    xbf[i] = ((const unsigned int*)x)[i];
  }
}

// ---------------- CSR build -------------------------------------------------
__global__ void k_count(const int* __restrict__ ei, int* __restrict__ deg,
                        const int* __restrict__ flags, int ne) {
  int e = blockIdx.x * 256 + threadIdx.x;
  if (e >= ne) return;
  int d = flags[1] ? ei[2 * ((size_t)ne + e)] : ei[(size_t)ne + e];
  atomicAdd(&deg[d], 1);
}

__global__ __launch_bounds__(256) void k_scanA(const int* __restrict__ deg,
                                               int* __restrict__ rowptr,
                                               int* __restrict__ part) {
  __shared__ int sh[256];
  int t = threadIdx.x;
  int i = blockIdx.x * 256 + t;
  int v = (i < N_NODES) ? deg[i] : 0;
  sh[t] = v;
  __syncthreads();
  for (int o = 1; o < 256; o <<= 1) {
    int a = sh[t];
    int b = (t >= o) ? sh[t - o] : 0;
    __syncthreads();
    sh[t] = a + b;
    __syncthreads();
  }
  if (i < N_NODES) rowptr[i] = sh[t] - v;   // local exclusive
  if (t == 255) part[blockIdx.x] = sh[255];
}

__global__ __launch_bounds__(256) void k_scanB(int* __restrict__ part,
                                               int* __restrict__ rowptr) {
  __shared__ int sh[256];
  int t = threadIdx.x;
  int v = (t < NBLK) ? part[t] : 0;
  sh[t] = v;
  __syncthreads();
  for (int o = 1; o < 256; o <<= 1) {
    int a = sh[t];
    int b = (t >= o) ? sh[t - o] : 0;
    __syncthreads();
    sh[t] = a + b;
    __syncthreads();
  }
  if (t < NBLK) part[t] = sh[t] - v;   // exclusive base per block
  if (t == 0) rowptr[N_NODES] = sh[255];
}

__global__ __launch_bounds__(256) void k_scanC(int* __restrict__ rowptr,
                                               const int* __restrict__ part,
                                               int* __restrict__ cur) {
  int i = blockIdx.x * 256 + threadIdx.x;
  if (i < N_NODES) {
    int r = rowptr[i] + part[blockIdx.x];
    rowptr[i] = r;
    cur[i] = r;
  }
}

__global__ void k_fill(const int* __restrict__ ei, int* __restrict__ cur,
                       int* __restrict__ elist, const int* __restrict__ flags,
                       int ne) {
  int e = blockIdx.x * 256 + threadIdx.x;
  if (e >= ne) return;
  bool fe64 = flags[1] != 0;
  int s = fe64 ? ei[2 * (size_t)e] : ei[e];
  int d = fe64 ? ei[2 * ((size_t)ne + e)] : ei[(size_t)ne + e];
  int pos = atomicAdd(&cur[d], 1);
  elist[pos] = s;
}

// ---------------- gather aggregation (one wave per node, bf16 source) -------
// h0[node] = bf16( x[node] + sum_{s in in(node)} x[s] ) via int32 fixed-point
__global__ __launch_bounds__(256) void k_gather(
    const unsigned int* __restrict__ xbf, const int* __restrict__ rowptr,
    const int* __restrict__ elist, unsigned int* __restrict__ h0) {
  int node = blockIdx.x * 4 + (threadIdx.x >> 6);
  if (node >= N_NODES) return;
  int lane = threadIdx.x & 63;
  int s0 = rowptr[node], s1 = rowptr[node + 1];
  unsigned int px = xbf[(size_t)node * (D_IN / 2) + lane];
  int a0 = __float2int_rn(__uint_as_float((px & 0xFFFFu) << 16) * AGG_SCALE);
  int a1 = __float2int_rn(__uint_as_float(px & 0xFFFF0000u) * AGG_SCALE);
  for (int j = s0; j < s1; ++j) {
    int s = elist[j];
    unsigned int p = xbf[(size_t)s * (D_IN / 2) + lane];
    a0 += __float2int_rn(__uint_as_float((p & 0xFFFFu) << 16) * AGG_SCALE);
    a1 += __float2int_rn(__uint_as_float(p & 0xFFFF0000u) * AGG_SCALE);
  }
  unsigned int lo = f2bf((float)a0 * AGG_INV);
  unsigned int hi = f2bf((float)a1 * AGG_INV);
  h0[(size_t)node * (D_IN / 2) + lane] = lo | (hi << 16);
}

// ---------------- MFMA GEMM: C = act(A @ W + bias), BK=64 ------------------
// grid = (Nc/BN, M-tiles): A-tile sharers are dispatch-adjacent -> L3 reuse.
// ACT: 0 = LeakyReLU(1.5), 1 = ReLU, 2 = none. OUTF32: write f32 else bf16.
template <int ACT, bool OUTF32>
__global__ __launch_bounds__(256, 2) void gemm_bt(
    const unsigned short* __restrict__ A,
    const unsigned short* __restrict__ BT,
    const void* __restrict__ bias, const int* __restrict__ flags,
    void* __restrict__ Cout, int M, int K, int Nc) {
  __shared__ __align__(16) unsigned short smem[BM * BK + BN * BK];  // 32 KB
  unsigned short* As = smem;
  unsigned short* Bs = smem + BM * BK;

  const int tid  = threadIdx.x;
  const int wave = tid >> 6;
  const int lane = tid & 63;
  const int quad = lane >> 4;
  const int l15  = lane & 15;
  const int n0 = blockIdx.x * BN;
  const int m0 = blockIdx.y * BM;
  const int wm = (wave >> 1) * 64;
  const int wn = (wave & 1) * 64;
  const bool fm = flags[0] != 0;

  v4f acc[4][4];
#pragma unroll
  for (int i = 0; i < 4; ++i)
#pragma unroll
    for (int j = 0; j < 4; ++j) acc[i][j] = (v4f){0.f, 0.f, 0.f, 0.f};

  const int nK = K / BK;   // 8 for K=512, 2 for K=128
  for (int kt = 0; kt < nK; ++kt) {
    const int k0 = kt * BK;
    __syncthreads();  // previous-iter LDS reads done
    // Stage A/B tiles: 1024 16B chunks each (row = L>>3, slot = L&7); slot
    // holds global chunk slot^(row&7) -> XOR-swizzled fragment reads.
#pragma unroll
    for (int it = 0; it < 4; ++it) {
      int L = tid + it * 256;
      int row = L >> 3;
      int c = (L & 7) ^ (row & 7);
      int gr = m0 + row;
      gr = gr < M ? gr : (M - 1);
      gload_lds16(A + (size_t)gr * K + (k0 + c * 8), As + (size_t)L * 8);
      int gn = n0 + row;  // Nc multiple of 128 -> always valid
      gload_lds16(BT + (size_t)gn * K + (k0 + c * 8), Bs + (size_t)L * 8);
    }
    __syncthreads();  // staging drained

#pragma unroll
    for (int h = 0; h < 2; ++h) {
      v8bf af[4], bfr[4];
#pragma unroll
      for (int mi = 0; mi < 4; ++mi) {
        int r = wm + mi * 16 + l15;
        int s = (h * 4 + quad) ^ (r & 7);
        af[mi] = *(const v8bf*)(As + (r * 8 + s) * 8);
      }
#pragma unroll
      for (int ni = 0; ni < 4; ++ni) {
        int r = wn + ni * 16 + l15;
        int s = (h * 4 + quad) ^ (r & 7);
        bfr[ni] = *(const v8bf*)(Bs + (r * 8 + s) * 8);
      }
#pragma unroll
      for (int mi = 0; mi < 4; ++mi)
#pragma unroll
        for (int ni = 0; ni < 4; ++ni)
          acc[mi][ni] = __builtin_amdgcn_mfma_f32_16x16x32_bf16(
              af[mi], bfr[ni], acc[mi][ni], 0, 0, 0);
    }
  }

  // Bias + activation (C/D layout: col = lane&15, row = quad*4 + reg)
  float bv[4];
#pragma unroll
  for (int ni = 0; ni < 4; ++ni) {
    int col = n0 + wn + ni * 16 + l15;
    bv[ni] = fm ? ((const float*)bias)[col]
                : bf2f(((const unsigned short*)bias)[col]);
  }
#pragma unroll
  for (int mi = 0; mi < 4; ++mi)
#pragma unroll
    for (int ni = 0; ni < 4; ++ni)
#pragma unroll
      for (int rg = 0; rg < 4; ++rg) {
        float v = acc[mi][ni][rg] + bv[ni];
        if (ACT == 0) v = v > 0.f ? v : 1.5f * v;
        if (ACT == 1) v = v > 0.f ? v : 0.f;
        acc[mi][ni][rg] = v;
      }

  if (OUTF32) {
    // small GEMM (pooled path): scalar f32 stores are fine
#pragma unroll
    for (int ni = 0; ni < 4; ++ni) {
      int col = n0 + wn + ni * 16 + l15;
#pragma unroll
      for (int mi = 0; mi < 4; ++mi)
#pragma unroll
        for (int rg = 0; rg < 4; ++rg) {
          int row = m0 + wm + mi * 16 + quad * 4 + rg;
          if (row < M)
            ((float*)Cout)[(size_t)row * Nc + col] = acc[mi][ni][rg];
        }
    }
    return;
  }

  // Coalesced bf16 epilogue: two 64-row passes staged through LDS.
  // Ct stride 264B -> ds_write_b16 conflict-free (banks 8*quad + l15/2).
  unsigned short* Ct = smem;   // 64*132*2 = 16896 B <= 32 KB
  __syncthreads();             // all waves done with As/Bs
#pragma unroll
  for (int h = 0; h < 2; ++h) {
    if ((wave >> 1) == h) {
#pragma unroll
      for (int mi = 0; mi < 4; ++mi)
#pragma unroll
        for (int ni = 0; ni < 4; ++ni)
#pragma unroll
          for (int rg = 0; rg < 4; ++rg) {
            int lr = mi * 16 + quad * 4 + rg;        // 0..63
            int c = wn + ni * 16 + l15;              // 0..127
            Ct[lr * CT_SW + c] = f2bf(acc[mi][ni][rg]);
          }
    }
    __syncthreads();
    int r = tid >> 2;              // 0..63
    int jj = tid & 3;
    int grow = m0 + h * 64 + r;
    if (grow < M) {
      unsigned short* base = (unsigned short*)Cout + (size_t)grow * Nc + n0;
#pragma unroll
      for (int p = 0; p < 4; ++p) {
        v4i val = *(const v4i*)(Ct + r * CT_SW + jj * 32 + p * 8);
        *(v4i*)(base + jj * 32 + p * 8) = val;
      }
    }
    __syncthreads();
  }
}

// ---------------- mean pool over sorted batch ------------------------------
__global__ __launch_bounds__(256) void k_pool(
    const unsigned short* __restrict__ h, const int* __restrict__ batch,
    const int* __restrict__ flags, unsigned short* __restrict__ pooled) {
  __shared__ int bounds[2];
  int g = blockIdx.x;
  int t = threadIdx.x;
  bool b64 = flags[2] != 0;
  if (t < 2) {
    int key = g + t;
    int lo = 0, hi = N_NODES;
    while (lo < hi) {
      int mid = (lo + hi) >> 1;
      int bv = b64 ? batch[2 * (size_t)mid] : batch[mid];
      if (bv < key) lo = mid + 1; else hi = mid;
    }
    bounds[t] = lo;
  }
  __syncthreads();
  int s0 = bounds[0], s1 = bounds[1];
  float a0 = 0.f, a1 = 0.f;
  for (int r = s0; r < s1; ++r) {
    a0 += bf2f(h[(size_t)r * D_H + t]);
    a1 += bf2f(h[(size_t)r * D_H + t + 256]);
  }
  float inv = 1.0f / fmaxf((float)(s1 - s0), 1.0f);
  pooled[(size_t)g * D_H + t] = f2bf(a0 * inv);
  pooled[(size_t)g * D_H + t + 256] = f2bf(a1 * inv);
}

// ---------------- row L2-normalize -----------------------------------------
__global__ __launch_bounds__(256) void k_norm(const float* __restrict__ of,
                                              const int* __restrict__ flags,
                                              void* __restrict__ out) {
  __shared__ float red[4];
  int g = blockIdx.x, t = threadIdx.x;
  float v = of[g * D_OUT + t];
  float s = v * v;
#pragma unroll
  for (int o = 32; o > 0; o >>= 1) s += __shfl_xor(s, o, 64);
  if ((t & 63) == 0) red[t >> 6] = s;
  __syncthreads();
  float tot = red[0] + red[1] + red[2] + red[3];
  float inv = 1.0f / fmaxf(sqrtf(tot), 1e-12f);
  float r = v * inv;
  if (flags[0])
    ((float*)out)[g * D_OUT + t] = r;
  else
    ((unsigned short*)out)[g * D_OUT + t] = f2bf(r);
}

// ---------------- launcher --------------------------------------------------
extern "C" void kernel_launch(void* const* d_in, const int* in_sizes, int n_in,
                              void* d_out, int out_size, void* d_ws,
                              size_t ws_size, hipStream_t stream) {
  const void* x    = d_in[0];
  const int* ei    = (const int*)d_in[1];
  const int* batch = (const int*)d_in[2];
  const void* W1 = d_in[3];
  const void* b1 = d_in[4];
  const void* W2 = d_in[5];
  const void* b2 = d_in[6];
  const void* W3 = d_in[7];
  const void* b3 = d_in[8];
  const void* W4 = d_in[9];
  const void* b4 = d_in[10];
  const void* Wl = d_in[11];
  const void* bl = d_in[12];

  char* ws = (char*)d_ws;
  size_t off = 0;
  auto alloc = [&](size_t bytes) {
    void* p = ws + off;
    off += (bytes + 255) & ~(size_t)255;
    return p;
  };
  int* flags           = (int*)alloc(64);
  unsigned short* W1T  = (unsigned short*)alloc((size_t)D_IN * D_H * 2);
  unsigned short* W2T  = (unsigned short*)alloc((size_t)D_H * D_H * 2);
  unsigned short* W3T  = (unsigned short*)alloc((size_t)D_H * D_H * 2);
  unsigned short* W4T  = (unsigned short*)alloc((size_t)D_H * D_H * 2);
  unsigned short* WlT  = (unsigned short*)alloc((size_t)D_H * D_OUT * 2);
  unsigned short* pooled = (unsigned short*)alloc((size_t)N_GRAPHS * D_H * 2);
  float* outf          = (float*)alloc((size_t)N_GRAPHS * D_OUT * 4);
  int* deg    = (int*)alloc((size_t)N_NODES * 4);
  int* rowptr = (int*)alloc(((size_t)N_NODES + 1) * 4);
  int* cur    = (int*)alloc((size_t)N_NODES * 4);
  int* part   = (int*)alloc((size_t)NBLK * 4);
  int* elist  = (int*)alloc((size_t)N_EDGES * 4);
  // two big slots (51.2 MB each), aliased:
  //   S1: xbf(12.8MB) -> dead after gather -> hA(bf16)
  //   S2: h0(12.8MB)  -> dead after GEMM1  -> hB(bf16)
  void* S1 = alloc((size_t)N_NODES * D_H * 2);
  void* S2 = alloc((size_t)N_NODES * D_H * 2);
  unsigned int* xbf  = (unsigned int*)S1;
  unsigned short* hA = (unsigned short*)S1;
  unsigned int* h0u  = (unsigned int*)S2;
  unsigned short* h0 = (unsigned short*)S2;
  unsigned short* hB = (unsigned short*)S2;

  k_prep<<<NBLK, 256, 0, stream>>>(x, ei, batch, deg, flags);

  k_transpose_all<<<(983040 + 255) / 256, 256, 0, stream>>>(
      W1, W2, W3, W4, Wl, W1T, W2T, W3T, W4T, WlT, flags);
  k_cvtx<<<(N_NODES * D_IN / 2 + 255) / 256, 256, 0, stream>>>(x, flags, xbf);

  // CSR build + gather aggregation
  k_count<<<(N_EDGES + 255) / 256, 256, 0, stream>>>(ei, deg, flags, N_EDGES);
  k_scanA<<<NBLK, 256, 0, stream>>>(deg, rowptr, part);
  k_scanB<<<1, 256, 0, stream>>>(part, rowptr);
  k_scanC<<<NBLK, 256, 0, stream>>>(rowptr, part, cur);
  k_fill<<<(N_EDGES + 255) / 256, 256, 0, stream>>>(ei, cur, elist, flags, N_EDGES);
  k_gather<<<(N_NODES + 3) / 4, 256, 0, stream>>>(xbf, rowptr, elist, h0u);

  dim3 gN(D_H / BN, (N_NODES + BM - 1) / BM);   // (n-tiles, m-tiles)
  gemm_bt<0, false><<<gN, 256, 0, stream>>>(h0, W1T, b1, flags, hA, N_NODES, D_IN, D_H);
  gemm_bt<1, false><<<gN, 256, 0, stream>>>(hA, W2T, b2, flags, hB, N_NODES, D_H, D_H);
  gemm_bt<1, false><<<gN, 256, 0, stream>>>(hB, W3T, b3, flags, hA, N_NODES, D_H, D_H);
  gemm_bt<2, false><<<gN, 256, 0, stream>>>(hA, W4T, b4, flags, hB, N_NODES, D_H, D_H);

  k_pool<<<N_GRAPHS, 256, 0, stream>>>(hB, batch, flags, pooled);

  dim3 g5(D_OUT / BN, N_GRAPHS / BM);
  gemm_bt<2, true><<<g5, 256, 0, stream>>>(pooled, WlT, bl, flags, outf, N_GRAPHS, D_H, D_OUT);

  k_norm<<<N_GRAPHS, 256, 0, stream>>>(outf, flags, (unsigned short*)d_out);
}

// Round 7
// 491.414 us; speedup vs baseline: 1.9073x; 1.0322x over previous
//
#include <hip/hip_runtime.h>
#include <hip/hip_bf16.h>
#include <cstdint>
#include <cstddef>

#define N_NODES 50000
#define N_EDGES 800000
#define D_IN 128
#define D_H 512
#define D_OUT 256
#define N_GRAPHS 512

#define BM 128
#define BN 128
#define BK 64
#define NBLK ((N_NODES + 255) / 256)   // 196
#define CT_SW 132                      // C-tile LDS stride in ushorts (264 B)
#define N_MT 391                       // m-tiles for M=50000
#define MT_PER_XCD 49                  // ceil(391/8)

// fixed-point scale for deterministic integer aggregation
#define AGG_SCALE 65536.0f
#define AGG_INV (1.0f / 65536.0f)

typedef __bf16 v8bf __attribute__((ext_vector_type(8)));
typedef float v4f __attribute__((ext_vector_type(4)));
typedef int v4i __attribute__((ext_vector_type(4)));

__device__ __forceinline__ float bf2f(unsigned short b) {
  return __uint_as_float(((unsigned int)b) << 16);
}
__device__ __forceinline__ unsigned short f2bf(float f) {
  unsigned int u = __float_as_uint(f);
  u += 0x7FFFu + ((u >> 16) & 1u);   // RNE
  return (unsigned short)(u >> 16);
}

__device__ __forceinline__ void gload_lds16(const void* g, void* l) {
  __builtin_amdgcn_global_load_lds(
      (const __attribute__((address_space(1))) void*)g,
      (__attribute__((address_space(3))) void*)l, 16, 0, 0);
}

// ---------------- prep: zero deg + dtype detect (block 0) -------------------
__global__ __launch_bounds__(256) void k_prep(const void* __restrict__ x,
                                              const void* __restrict__ ei,
                                              const void* __restrict__ batch,
                                              int* __restrict__ deg,
                                              int* __restrict__ flags) {
  int i = blockIdx.x * 256 + threadIdx.x;
  if (i < N_NODES) deg[i] = 0;
  if (blockIdx.x != 0) return;
  __shared__ int cnt[3];
  int t = threadIdx.x;
  if (t < 3) cnt[t] = 0;
  __syncthreads();
  const unsigned short* xs = (const unsigned short*)x;
  int c0 = 0;
  for (int k = t; k < 4096; k += 256) {
    unsigned int e = (xs[k] >> 7) & 0xFFu;
    if (e >= 0x90u) c0++;   // |v|>=2^17 as bf16: impossible for N(0,1)
  }
  atomicAdd(&cnt[0], c0);
  const int* e32 = (const int*)ei;
  int c1 = 0;
  for (int k = t; k < 512; k += 256)
    if (e32[2 * k + 1] != 0) c1++;   // int64 -> high words all zero
  atomicAdd(&cnt[1], c1);
  const int* b32 = (const int*)batch;
  int c2 = 0;
  {
    int w = (N_NODES - 512) + 2 * t + 1;   // odd word near tail, < N_NODES
    if (b32[w] != 0) c2++;
  }
  atomicAdd(&cnt[2], c2);
  __syncthreads();
  if (t == 0) {
    flags[0] = (cnt[0] > 16) ? 1 : 0;
    flags[1] = (cnt[1] == 0) ? 1 : 0;
    flags[2] = (cnt[2] == 0) ? 1 : 0;
  }
}

// ---------------- fused weight transposes (B^T layout) ----------------------
__global__ void k_transpose_all(const void* W1, const void* W2, const void* W3,
                                const void* W4, const void* Wl,
                                unsigned short* W1T, unsigned short* W2T,
                                unsigned short* W3T, unsigned short* W4T,
                                unsigned short* WlT,
                                const int* __restrict__ flags) {
  int i = blockIdx.x * 256 + threadIdx.x;
  const void* src;
  unsigned short* dst;
  int R, C, j;
  if (i < 65536)            { src = W1; dst = W1T; R = 128; C = 512; j = i; }
  else if (i < 327680)      { src = W2; dst = W2T; R = 512; C = 512; j = i - 65536; }
  else if (i < 589824)      { src = W3; dst = W3T; R = 512; C = 512; j = i - 327680; }
  else if (i < 851968)      { src = W4; dst = W4T; R = 512; C = 512; j = i - 589824; }
  else if (i < 983040)      { src = Wl; dst = WlT; R = 512; C = 256; j = i - 851968; }
  else return;
  int r = j / C, c = j - r * C;
  unsigned short v = flags[0] ? f2bf(((const float*)src)[j])
                              : ((const unsigned short*)src)[j];
  dst[c * R + r] = v;
}

// ---------------- x -> bf16 (halves gather traffic) -------------------------
__global__ __launch_bounds__(256) void k_cvtx(const void* __restrict__ x,
                                              const int* __restrict__ flags,
                                              unsigned int* __restrict__ xbf) {
  int i = blockIdx.x * 256 + threadIdx.x;   // dword index (2 bf16)
  if (i >= N_NODES * D_IN / 2) return;
  if (flags[0]) {
    const float* xf = (const float*)x + (size_t)i * 2;
    xbf[i] = (unsigned int)f2bf(xf[0]) | ((unsigned int)f2bf(xf[1]) << 16);
  } else {
    xbf[i] = ((const unsigned int*)x)[i];
  }
}

// ---------------- CSR build -------------------------------------------------
__global__ void k_count(const int* __restrict__ ei, int* __restrict__ deg,
                        const int* __restrict__ flags, int ne) {
  int e = blockIdx.x * 256 + threadIdx.x;
  if (e >= ne) return;
  int d = flags[1] ? ei[2 * ((size_t)ne + e)] : ei[(size_t)ne + e];
  atomicAdd(&deg[d], 1);
}

__global__ __launch_bounds__(256) void k_scanA(const int* __restrict__ deg,
                                               int* __restrict__ rowptr,
                                               int* __restrict__ part) {
  __shared__ int sh[256];
  int t = threadIdx.x;
  int i = blockIdx.x * 256 + t;
  int v = (i < N_NODES) ? deg[i] : 0;
  sh[t] = v;
  __syncthreads();
  for (int o = 1; o < 256; o <<= 1) {
    int a = sh[t];
    int b = (t >= o) ? sh[t - o] : 0;
    __syncthreads();
    sh[t] = a + b;
    __syncthreads();
  }
  if (i < N_NODES) rowptr[i] = sh[t] - v;   // local exclusive
  if (t == 255) part[blockIdx.x] = sh[255];
}

__global__ __launch_bounds__(256) void k_scanB(int* __restrict__ part,
                                               int* __restrict__ rowptr) {
  __shared__ int sh[256];
  int t = threadIdx.x;
  int v = (t < NBLK) ? part[t] : 0;
  sh[t] = v;
  __syncthreads();
  for (int o = 1; o < 256; o <<= 1) {
    int a = sh[t];
    int b = (t >= o) ? sh[t - o] : 0;
    __syncthreads();
    sh[t] = a + b;
    __syncthreads();
  }
  if (t < NBLK) part[t] = sh[t] - v;   // exclusive base per block
  if (t == 0) rowptr[N_NODES] = sh[255];
}

__global__ __launch_bounds__(256) void k_scanC(int* __restrict__ rowptr,
                                               const int* __restrict__ part,
                                               int* __restrict__ cur) {
  int i = blockIdx.x * 256 + threadIdx.x;
  if (i < N_NODES) {
    int r = rowptr[i] + part[blockIdx.x];
    rowptr[i] = r;
    cur[i] = r;
  }
}

__global__ void k_fill(const int* __restrict__ ei, int* __restrict__ cur,
                       int* __restrict__ elist, const int* __restrict__ flags,
                       int ne) {
  int e = blockIdx.x * 256 + threadIdx.x;
  if (e >= ne) return;
  bool fe64 = flags[1] != 0;
  int s = fe64 ? ei[2 * (size_t)e] : ei[e];
  int d = fe64 ? ei[2 * ((size_t)ne + e)] : ei[(size_t)ne + e];
  int pos = atomicAdd(&cur[d], 1);
  elist[pos] = s;
}

// ---------------- gather aggregation (one wave per node, bf16 source) -------
__global__ __launch_bounds__(256) void k_gather(
    const unsigned int* __restrict__ xbf, const int* __restrict__ rowptr,
    const int* __restrict__ elist, unsigned int* __restrict__ h0) {
  int node = blockIdx.x * 4 + (threadIdx.x >> 6);
  if (node >= N_NODES) return;
  int lane = threadIdx.x & 63;
  int s0 = rowptr[node], s1 = rowptr[node + 1];
  unsigned int px = xbf[(size_t)node * (D_IN / 2) + lane];
  int a0 = __float2int_rn(__uint_as_float((px & 0xFFFFu) << 16) * AGG_SCALE);
  int a1 = __float2int_rn(__uint_as_float(px & 0xFFFF0000u) * AGG_SCALE);
  for (int j = s0; j < s1; ++j) {
    int s = elist[j];
    unsigned int p = xbf[(size_t)s * (D_IN / 2) + lane];
    a0 += __float2int_rn(__uint_as_float((p & 0xFFFFu) << 16) * AGG_SCALE);
    a1 += __float2int_rn(__uint_as_float(p & 0xFFFF0000u) * AGG_SCALE);
  }
  unsigned int lo = f2bf((float)a0 * AGG_INV);
  unsigned int hi = f2bf((float)a1 * AGG_INV);
  h0[(size_t)node * (D_IN / 2) + lane] = lo | (hi << 16);
}

// ---------------- MFMA GEMM: C = act(A @ W + bias) -------------------------
// Double-buffered LDS K-loop: stage(k+1) issued BEFORE compute(k) so the
// vmcnt(0) drain at the next barrier lands after a full compute phase.
// SWZ: XCD-aware mapping — blockIdx.x&7 selects XCD (round-robin dispatch);
// the 4 n-tiles sharing an A m-tile are consecutive within one XCD -> A-tile
// served from that XCD's L2 (fix for R6's 2x A FETCH).
// ACT: 0 = LeakyReLU(1.5), 1 = ReLU, 2 = none. OUTF32: write f32 else bf16.
template <int ACT, bool OUTF32, bool SWZ>
__global__ __launch_bounds__(256, 2) void gemm_bt(
    const unsigned short* __restrict__ A,
    const unsigned short* __restrict__ BT,
    const void* __restrict__ bias, const int* __restrict__ flags,
    void* __restrict__ Cout, int M, int K, int Nc) {
  __shared__ __align__(16) unsigned short smem[2][BM * BK + BN * BK];  // 64 KB

  const int tid  = threadIdx.x;
  const int wave = tid >> 6;
  const int lane = tid & 63;
  const int quad = lane >> 4;
  const int l15  = lane & 15;
  int m0, n0;
  if (SWZ) {
    int xcd = blockIdx.x & 7;
    int l = blockIdx.x >> 3;                 // 0..195
    int mt = xcd * MT_PER_XCD + (l >> 2);    // 49 m-tiles per XCD
    if (mt >= N_MT) return;                  // 8 padded blocks exit
    m0 = mt * BM;
    n0 = (l & 3) * BN;
  } else {
    n0 = blockIdx.x * BN;
    m0 = blockIdx.y * BM;
  }
  const int wm = (wave >> 1) * 64;
  const int wn = (wave & 1) * 64;
  const bool fm = flags[0] != 0;

  v4f acc[4][4];
#pragma unroll
  for (int i = 0; i < 4; ++i)
#pragma unroll
    for (int j = 0; j < 4; ++j) acc[i][j] = (v4f){0.f, 0.f, 0.f, 0.f};

  // stage K-tile kt into LDS buffer buf (1024 16B chunks per matrix;
  // row = L>>3, slot = L&7 holds global chunk slot^(row&7) -> XOR swizzle)
  auto stage = [&](int kt, int buf) {
    const int k0 = kt * BK;
    unsigned short* As = smem[buf];
    unsigned short* Bs = smem[buf] + BM * BK;
#pragma unroll
    for (int it = 0; it < 4; ++it) {
      int L = tid + it * 256;
      int row = L >> 3;
      int c = (L & 7) ^ (row & 7);
      int gr = m0 + row;
      gr = gr < M ? gr : (M - 1);
      gload_lds16(A + (size_t)gr * K + (k0 + c * 8), As + (size_t)L * 8);
      int gn = n0 + row;  // Nc multiple of 128 -> always valid
      gload_lds16(BT + (size_t)gn * K + (k0 + c * 8), Bs + (size_t)L * 8);
    }
  };

  const int nK = K / BK;   // 8 for K=512, 2 for K=128
  stage(0, 0);
  for (int kt = 0; kt < nK; ++kt) {
    __syncthreads();   // drains vmcnt(0): buf[kt&1] staging complete
    if (kt + 1 < nK) stage(kt + 1, (kt + 1) & 1);
    const unsigned short* As = smem[kt & 1];
    const unsigned short* Bs = smem[kt & 1] + BM * BK;
#pragma unroll
    for (int h = 0; h < 2; ++h) {
      v8bf af[4], bfr[4];
#pragma unroll
      for (int mi = 0; mi < 4; ++mi) {
        int r = wm + mi * 16 + l15;
        int s = (h * 4 + quad) ^ (r & 7);
        af[mi] = *(const v8bf*)(As + (r * 8 + s) * 8);
      }
#pragma unroll
      for (int ni = 0; ni < 4; ++ni) {
        int r = wn + ni * 16 + l15;
        int s = (h * 4 + quad) ^ (r & 7);
        bfr[ni] = *(const v8bf*)(Bs + (r * 8 + s) * 8);
      }
#pragma unroll
      for (int mi = 0; mi < 4; ++mi)
#pragma unroll
        for (int ni = 0; ni < 4; ++ni)
          acc[mi][ni] = __builtin_amdgcn_mfma_f32_16x16x32_bf16(
              af[mi], bfr[ni], acc[mi][ni], 0, 0, 0);
    }
  }

  // Bias + activation (C/D layout: col = lane&15, row = quad*4 + reg)
  float bv[4];
#pragma unroll
  for (int ni = 0; ni < 4; ++ni) {
    int col = n0 + wn + ni * 16 + l15;
    bv[ni] = fm ? ((const float*)bias)[col]
                : bf2f(((const unsigned short*)bias)[col]);
  }
#pragma unroll
  for (int mi = 0; mi < 4; ++mi)
#pragma unroll
    for (int ni = 0; ni < 4; ++ni)
#pragma unroll
      for (int rg = 0; rg < 4; ++rg) {
        float v = acc[mi][ni][rg] + bv[ni];
        if (ACT == 0) v = v > 0.f ? v : 1.5f * v;
        if (ACT == 1) v = v > 0.f ? v : 0.f;
        acc[mi][ni][rg] = v;
      }

  if (OUTF32) {
#pragma unroll
    for (int ni = 0; ni < 4; ++ni) {
      int col = n0 + wn + ni * 16 + l15;
#pragma unroll
      for (int mi = 0; mi < 4; ++mi)
#pragma unroll
        for (int rg = 0; rg < 4; ++rg) {
          int row = m0 + wm + mi * 16 + quad * 4 + rg;
          if (row < M)
            ((float*)Cout)[(size_t)row * Nc + col] = acc[mi][ni][rg];
        }
    }
    return;
  }

  // Coalesced bf16 epilogue: two 64-row passes staged through LDS (buf0;
  // last K-iter read buf[(nK-1)&1]=buf1 for even nK -> no overlap).
  unsigned short* Ct = smem[0];   // 64*132*2 = 16896 B
  __syncthreads();
#pragma unroll
  for (int h = 0; h < 2; ++h) {
    if ((wave >> 1) == h) {
#pragma unroll
      for (int mi = 0; mi < 4; ++mi)
#pragma unroll
        for (int ni = 0; ni < 4; ++ni)
#pragma unroll
          for (int rg = 0; rg < 4; ++rg) {
            int lr = mi * 16 + quad * 4 + rg;        // 0..63
            int c = wn + ni * 16 + l15;              // 0..127
            Ct[lr * CT_SW + c] = f2bf(acc[mi][ni][rg]);
          }
    }
    __syncthreads();
    int r = tid >> 2;              // 0..63
    int jj = tid & 3;
    int grow = m0 + h * 64 + r;
    if (grow < M) {
      unsigned short* base = (unsigned short*)Cout + (size_t)grow * Nc + n0;
#pragma unroll
      for (int p = 0; p < 4; ++p) {
        v4i val = *(const v4i*)(Ct + r * CT_SW + jj * 32 + p * 8);
        *(v4i*)(base + jj * 32 + p * 8) = val;
      }
    }
    __syncthreads();
  }
}

// ---------------- mean pool over sorted batch ------------------------------
__global__ __launch_bounds__(256) void k_pool(
    const unsigned short* __restrict__ h, const int* __restrict__ batch,
    const int* __restrict__ flags, unsigned short* __restrict__ pooled) {
  __shared__ int bounds[2];
  int g = blockIdx.x;
  int t = threadIdx.x;
  bool b64 = flags[2] != 0;
  if (t < 2) {
    int key = g + t;
    int lo = 0, hi = N_NODES;
    while (lo < hi) {
      int mid = (lo + hi) >> 1;
      int bv = b64 ? batch[2 * (size_t)mid] : batch[mid];
      if (bv < key) lo = mid + 1; else hi = mid;
    }
    bounds[t] = lo;
  }
  __syncthreads();
  int s0 = bounds[0], s1 = bounds[1];
  float a0 = 0.f, a1 = 0.f;
  for (int r = s0; r < s1; ++r) {
    a0 += bf2f(h[(size_t)r * D_H + t]);
    a1 += bf2f(h[(size_t)r * D_H + t + 256]);
  }
  float inv = 1.0f / fmaxf((float)(s1 - s0), 1.0f);
  pooled[(size_t)g * D_H + t] = f2bf(a0 * inv);
  pooled[(size_t)g * D_H + t + 256] = f2bf(a1 * inv);
}

// ---------------- row L2-normalize -----------------------------------------
__global__ __launch_bounds__(256) void k_norm(const float* __restrict__ of,
                                              const int* __restrict__ flags,
                                              void* __restrict__ out) {
  __shared__ float red[4];
  int g = blockIdx.x, t = threadIdx.x;
  float v = of[g * D_OUT + t];
  float s = v * v;
#pragma unroll
  for (int o = 32; o > 0; o >>= 1) s += __shfl_xor(s, o, 64);
  if ((t & 63) == 0) red[t >> 6] = s;
  __syncthreads();
  float tot = red[0] + red[1] + red[2] + red[3];
  float inv = 1.0f / fmaxf(sqrtf(tot), 1e-12f);
  float r = v * inv;
  if (flags[0])
    ((float*)out)[g * D_OUT + t] = r;
  else
    ((unsigned short*)out)[g * D_OUT + t] = f2bf(r);
}

// ---------------- launcher --------------------------------------------------
extern "C" void kernel_launch(void* const* d_in, const int* in_sizes, int n_in,
                              void* d_out, int out_size, void* d_ws,
                              size_t ws_size, hipStream_t stream) {
  const void* x    = d_in[0];
  const int* ei    = (const int*)d_in[1];
  const int* batch = (const int*)d_in[2];
  const void* W1 = d_in[3];
  const void* b1 = d_in[4];
  const void* W2 = d_in[5];
  const void* b2 = d_in[6];
  const void* W3 = d_in[7];
  const void* b3 = d_in[8];
  const void* W4 = d_in[9];
  const void* b4 = d_in[10];
  const void* Wl = d_in[11];
  const void* bl = d_in[12];

  char* ws = (char*)d_ws;
  size_t off = 0;
  auto alloc = [&](size_t bytes) {
    void* p = ws + off;
    off += (bytes + 255) & ~(size_t)255;
    return p;
  };
  int* flags           = (int*)alloc(64);
  unsigned short* W1T  = (unsigned short*)alloc((size_t)D_IN * D_H * 2);
  unsigned short* W2T  = (unsigned short*)alloc((size_t)D_H * D_H * 2);
  unsigned short* W3T  = (unsigned short*)alloc((size_t)D_H * D_H * 2);
  unsigned short* W4T  = (unsigned short*)alloc((size_t)D_H * D_H * 2);
  unsigned short* WlT  = (unsigned short*)alloc((size_t)D_H * D_OUT * 2);
  unsigned short* pooled = (unsigned short*)alloc((size_t)N_GRAPHS * D_H * 2);
  float* outf          = (float*)alloc((size_t)N_GRAPHS * D_OUT * 4);
  int* deg    = (int*)alloc((size_t)N_NODES * 4);
  int* rowptr = (int*)alloc(((size_t)N_NODES + 1) * 4);
  int* cur    = (int*)alloc((size_t)N_NODES * 4);
  int* part   = (int*)alloc((size_t)NBLK * 4);
  int* elist  = (int*)alloc((size_t)N_EDGES * 4);
  // two big slots (51.2 MB each), aliased:
  //   S1: xbf(12.8MB) -> dead after gather -> hA(bf16)
  //   S2: h0(12.8MB)  -> dead after GEMM1  -> hB(bf16)
  void* S1 = alloc((size_t)N_NODES * D_H * 2);
  void* S2 = alloc((size_t)N_NODES * D_H * 2);
  unsigned int* xbf  = (unsigned int*)S1;
  unsigned short* hA = (unsigned short*)S1;
  unsigned int* h0u  = (unsigned int*)S2;
  unsigned short* h0 = (unsigned short*)S2;
  unsigned short* hB = (unsigned short*)S2;

  k_prep<<<NBLK, 256, 0, stream>>>(x, ei, batch, deg, flags);

  k_transpose_all<<<(983040 + 255) / 256, 256, 0, stream>>>(
      W1, W2, W3, W4, Wl, W1T, W2T, W3T, W4T, WlT, flags);
  k_cvtx<<<(N_NODES * D_IN / 2 + 255) / 256, 256, 0, stream>>>(x, flags, xbf);

  // CSR build + gather aggregation
  k_count<<<(N_EDGES + 255) / 256, 256, 0, stream>>>(ei, deg, flags, N_EDGES);
  k_scanA<<<NBLK, 256, 0, stream>>>(deg, rowptr, part);
  k_scanB<<<1, 256, 0, stream>>>(part, rowptr);
  k_scanC<<<NBLK, 256, 0, stream>>>(rowptr, part, cur);
  k_fill<<<(N_EDGES + 255) / 256, 256, 0, stream>>>(ei, cur, elist, flags, N_EDGES);
  k_gather<<<(N_NODES + 3) / 4, 256, 0, stream>>>(xbf, rowptr, elist, h0u);

  const int gBig = 8 * MT_PER_XCD * 4;   // 1568 XCD-swizzled blocks
  gemm_bt<0, false, true><<<gBig, 256, 0, stream>>>(h0, W1T, b1, flags, hA, N_NODES, D_IN, D_H);
  gemm_bt<1, false, true><<<gBig, 256, 0, stream>>>(hA, W2T, b2, flags, hB, N_NODES, D_H, D_H);
  gemm_bt<1, false, true><<<gBig, 256, 0, stream>>>(hB, W3T, b3, flags, hA, N_NODES, D_H, D_H);
  gemm_bt<2, false, true><<<gBig, 256, 0, stream>>>(hA, W4T, b4, flags, hB, N_NODES, D_H, D_H);

  k_pool<<<N_GRAPHS, 256, 0, stream>>>(hB, batch, flags, pooled);

  dim3 g5(D_OUT / BN, N_GRAPHS / BM);
  gemm_bt<2, true, false><<<g5, 256, 0, stream>>>(pooled, WlT, bl, flags, outf, N_GRAPHS, D_H, D_OUT);

  k_norm<<<N_GRAPHS, 256, 0, stream>>>(outf, flags, (unsigned short*)d_out);
}